// Round 13
// baseline (2141.339 us; speedup 1.0000x reference)
//
#include <hip/hip_runtime.h>
#include <math.h>

#define NN 100000
#define NE 3200000
#define NGRAPH 8
#define DEPTH 10
#define LOCC 167
#define LOCP 176
#define BNEPS 1e-5f

typedef _Float16 h16;
typedef _Float16 h8 __attribute__((ext_vector_type(8)));
typedef float f4 __attribute__((ext_vector_type(4)));

__device__ __forceinline__ float h2f(h16 v) { return (float)v; }
__device__ __forceinline__ h16 f2h(float v) { return (h16)v; }

// ---------------- CSR build ----------------
__global__ void k_count(const int* __restrict__ dst, int* __restrict__ cnt) {
    int e = blockIdx.x * 256 + threadIdx.x;
    atomicAdd(&cnt[dst[e]], 1);
}

__global__ __launch_bounds__(256) void k_scan1(const int* __restrict__ cnt,
                                               int* __restrict__ row_start,
                                               int* __restrict__ bsum) {
    int i = blockIdx.x * 256 + threadIdx.x;
    int lane = threadIdx.x & 63, wid = threadIdx.x >> 6;
    int v = (i < NN) ? cnt[i] : 0;
    int orig = v;
    #pragma unroll
    for (int off = 1; off < 64; off <<= 1) {
        int u = __shfl_up(v, off, 64);
        if (lane >= off) v += u;
    }
    __shared__ int ws[4];
    if (lane == 63) ws[wid] = v;
    __syncthreads();
    int add = 0;
    for (int w = 0; w < wid; w++) add += ws[w];
    v += add;
    if (i < NN) row_start[i] = v - orig;
    if (threadIdx.x == 255) bsum[blockIdx.x] = v;
}

__global__ __launch_bounds__(512) void k_scan2(int* __restrict__ bsum, int nb) {
    int t = threadIdx.x, lane = t & 63, wid = t >> 6;
    int v = (t < nb) ? bsum[t] : 0;
    int orig = v;
    #pragma unroll
    for (int off = 1; off < 64; off <<= 1) {
        int u = __shfl_up(v, off, 64);
        if (lane >= off) v += u;
    }
    __shared__ int ws[8];
    if (lane == 63) ws[wid] = v;
    __syncthreads();
    int add = 0;
    for (int w = 0; w < wid; w++) add += ws[w];
    v += add;
    if (t < nb) bsum[t] = v - orig;
}

__global__ void k_scan3(const int* __restrict__ cnt, int* __restrict__ row_start,
                        const int* __restrict__ bsum, float* __restrict__ inv_cnt) {
    int i = blockIdx.x * 256 + threadIdx.x;
    if (i < NN) {
        row_start[i] += bsum[blockIdx.x];
        inv_cnt[i] = 1.0f / fmaxf((float)cnt[i], 1.0f);
    }
    if (i == 0) row_start[NN] = NE;
}

__global__ void k_fill(const int* __restrict__ src, const int* __restrict__ dst,
                       const int* __restrict__ row_start, int* __restrict__ cursor,
                       int* __restrict__ csr) {
    int e = blockIdx.x * 256 + threadIdx.x;
    int d = dst[e];
    int o = atomicAdd(&cursor[d], 1);
    csr[row_start[d] + o] = src[e];
}

// ---------------- input build ----------------
__global__ void k_build_x0(const float* __restrict__ pos, const float* __restrict__ nrm,
                           const float* __restrict__ cur, float* __restrict__ x,
                           h16* __restrict__ local) {
    int n = blockIdx.x * 256 + threadIdx.x;
    if (n >= NN) return;
    float v[7];
    v[0] = pos[n * 3 + 0]; v[1] = pos[n * 3 + 1]; v[2] = pos[n * 3 + 2];
    v[3] = nrm[n * 3 + 0]; v[4] = nrm[n * 3 + 1]; v[5] = nrm[n * 3 + 2];
    v[6] = cur[n];
    float* xr = x + (size_t)n * 16;
    #pragma unroll
    for (int c = 0; c < 7; c++) xr[c] = v[c];
    #pragma unroll
    for (int c = 7; c < 16; c++) xr[c] = 0.f;
    h16* lr = local + (size_t)n * LOCP;
    #pragma unroll
    for (int c = 0; c < 7; c++) lr[160 + c] = f2h(v[c]);
    #pragma unroll
    for (int c = LOCC; c < LOCP; c++) lr[c] = f2h(0.f);
}

// ---------------- SAGE: 4 lanes/node, 16 nodes/wave, float4 gathers, 8-deep ----------------
__global__ __launch_bounds__(256) void k_sage(
    const float* __restrict__ x, const int* __restrict__ row_start,
    const int* __restrict__ csr, const float* __restrict__ inv_cnt,
    const float* __restrict__ w_nb, const float* __restrict__ b_nb,
    const float* __restrict__ w_rt, int kin,
    float* __restrict__ h_out, float* __restrict__ ssum, float* __restrict__ ssq) {
    const float4* x4 = (const float4*)x;
    int t = threadIdx.x, lane = t & 63, wid = t >> 6;
    int n = blockIdx.x * 64 + wid * 16 + (lane >> 2);
    int q = lane & 3;
    bool valid = n < NN;
    int s = 0, e = 0;
    if (valid) { s = row_start[n]; e = row_start[n + 1]; }
    float ax = 0.f, ay = 0.f, az = 0.f, aw = 0.f;
    float bx = 0.f, by = 0.f, bz = 0.f, bw = 0.f;
    int j = s;
    for (; j + 7 < e; j += 8) {
        int a0 = csr[j], a1 = csr[j + 1], a2 = csr[j + 2], a3 = csr[j + 3];
        int a4 = csr[j + 4], a5 = csr[j + 5], a6 = csr[j + 6], a7 = csr[j + 7];
        float4 v0 = x4[a0 * 4 + q];
        float4 v1 = x4[a1 * 4 + q];
        float4 v2 = x4[a2 * 4 + q];
        float4 v3 = x4[a3 * 4 + q];
        float4 v4 = x4[a4 * 4 + q];
        float4 v5 = x4[a5 * 4 + q];
        float4 v6 = x4[a6 * 4 + q];
        float4 v7 = x4[a7 * 4 + q];
        ax += (v0.x + v1.x) + (v2.x + v3.x);
        ay += (v0.y + v1.y) + (v2.y + v3.y);
        az += (v0.z + v1.z) + (v2.z + v3.z);
        aw += (v0.w + v1.w) + (v2.w + v3.w);
        bx += (v4.x + v5.x) + (v6.x + v7.x);
        by += (v4.y + v5.y) + (v6.y + v7.y);
        bz += (v4.z + v5.z) + (v6.z + v7.z);
        bw += (v4.w + v5.w) + (v6.w + v7.w);
    }
    for (; j < e; j++) {
        float4 v = x4[csr[j] * 4 + q];
        ax += v.x; ay += v.y; az += v.z; aw += v.w;
    }
    ax += bx; ay += by; az += bz; aw += bw;
    float ic = valid ? inv_cnt[n] : 0.f;
    float agg[4] = {ax * ic, ay * ic, az * ic, aw * ic};
    float xn[4] = {0.f, 0.f, 0.f, 0.f};
    if (valid) {
        float4 v = x4[n * 4 + q];
        xn[0] = v.x; xn[1] = v.y; xn[2] = v.z; xn[3] = v.w;
    }
    float hc0 = 0.f, hc1 = 0.f, hc2 = 0.f, hc3 = 0.f;
    #pragma unroll
    for (int r = 0; r < 4; r++) {
        int kq = (q + r) & 3;
        int srcl = (lane & 60) | kq;
        float av[4], xv[4];
        #pragma unroll
        for (int c = 0; c < 4; c++) {
            av[c] = __shfl(agg[c], srcl, 64);
            xv[c] = __shfl(xn[c], srcl, 64);
        }
        #pragma unroll
        for (int kk = 0; kk < 4; kk++) {
            int k = kq * 4 + kk;
            if (k < kin) {
                float4 wn4 = *(const float4*)&w_nb[k * 16 + 4 * q];
                float4 wr4 = *(const float4*)&w_rt[k * 16 + 4 * q];
                hc0 = fmaf(av[kk], wn4.x, hc0); hc0 = fmaf(xv[kk], wr4.x, hc0);
                hc1 = fmaf(av[kk], wn4.y, hc1); hc1 = fmaf(xv[kk], wr4.y, hc1);
                hc2 = fmaf(av[kk], wn4.z, hc2); hc2 = fmaf(xv[kk], wr4.z, hc2);
                hc3 = fmaf(av[kk], wn4.w, hc3); hc3 = fmaf(xv[kk], wr4.w, hc3);
            }
        }
    }
    float4 b4 = *(const float4*)&b_nb[4 * q];
    hc0 += b4.x; hc1 += b4.y; hc2 += b4.z; hc3 += b4.w;
    if (!valid) { hc0 = 0.f; hc1 = 0.f; hc2 = 0.f; hc3 = 0.f; }
    else {
        *(float4*)&h_out[(size_t)n * 16 + 4 * q] = make_float4(hc0, hc1, hc2, hc3);
    }
    float s0 = hc0, s1 = hc1, s2 = hc2, s3 = hc3;
    float q0 = hc0 * hc0, q1 = hc1 * hc1, q2 = hc2 * hc2, q3 = hc3 * hc3;
    #pragma unroll
    for (int off = 4; off < 64; off <<= 1) {
        s0 += __shfl_xor(s0, off, 64); s1 += __shfl_xor(s1, off, 64);
        s2 += __shfl_xor(s2, off, 64); s3 += __shfl_xor(s3, off, 64);
        q0 += __shfl_xor(q0, off, 64); q1 += __shfl_xor(q1, off, 64);
        q2 += __shfl_xor(q2, off, 64); q3 += __shfl_xor(q3, off, 64);
    }
    if (lane < 4) {
        int slot = blockIdx.x & 63;
        float* ps = &ssum[slot * 16 + 4 * lane];
        float* pq = &ssq[slot * 16 + 4 * lane];
        atomicAdd(ps + 0, s0); atomicAdd(ps + 1, s1);
        atomicAdd(ps + 2, s2); atomicAdd(ps + 3, s3);
        atomicAdd(pq + 0, q0); atomicAdd(pq + 1, q1);
        atomicAdd(pq + 2, q2); atomicAdd(pq + 3, q3);
    }
}

// ---------------- fused BN-finalize + apply (per-layer stat slice, no cleanup) ----------------
__global__ void k_apply(const float* __restrict__ h,
                        const float* __restrict__ ssum, const float* __restrict__ ssq,
                        const float* __restrict__ g, const float* __restrict__ b,
                        float* __restrict__ x, h16* __restrict__ local, int colbase) {
    __shared__ float sscale[16], sshift[16];
    int t = threadIdx.x;
    if (t < 16) {
        float s = 0.f, q = 0.f;
        for (int sl = 0; sl < 64; sl++) {
            s += ssum[sl * 16 + t];
            q += ssq[sl * 16 + t];
        }
        float mean = s / (float)NN;
        float var = q / (float)NN - mean * mean;
        var = var > 0.f ? var : 0.f;
        float sc = g[t] / sqrtf(var + BNEPS);
        sscale[t] = sc;
        sshift[t] = b[t] - mean * sc;
    }
    __syncthreads();
    int i = blockIdx.x * 256 + t;
    int n = i >> 4, c = i & 15;
    float v = fmaf(h[i], sscale[c], sshift[c]);
    float e = v > 0.f ? v : expm1f(v);
    x[i] = e;
    local[(size_t)n * LOCP + colbase + c] = f2h(e);
}

// ---------------- BN finalize (GEMM layers): 64-slot reduce + self-clean ----------------
__global__ void k_bn_fin(float* __restrict__ ssum, float* __restrict__ ssq,
                         const float* __restrict__ g, const float* __restrict__ b,
                         float M, int C, float* __restrict__ scale, float* __restrict__ shift) {
    int c = blockIdx.x * blockDim.x + threadIdx.x;
    if (c >= C) return;
    float s = 0.f, q = 0.f;
    for (int sl = 0; sl < 64; sl++) {
        s += ssum[sl * C + c]; ssum[sl * C + c] = 0.f;
        q += ssq[sl * C + c];  ssq[sl * C + c] = 0.f;
    }
    float mean = s / M;
    float var = q / M - mean * mean;
    var = var > 0.f ? var : 0.f;
    float sc = g[c] / sqrtf(var + BNEPS);
    scale[c] = sc;
    shift[c] = b[c] - mean * sc;
}

// ---------------- weight prep: fragment-order Wt (hi+lo) ----------------
__global__ void k_wt(const float* __restrict__ W, const float* __restrict__ scale,
                     h16* __restrict__ WtH, h16* __restrict__ WtL,
                     int N, int Kin, int Kpad, int split, int gap) {
    int u = blockIdx.x * 256 + threadIdx.x;
    int nkc = Kpad >> 5;
    int total = (N >> 4) * nkc * 64;
    if (u >= total) return;
    int lane = u & 63;
    int fc = u >> 6;
    int kc = fc % nkc;
    int cs = fc / nkc;
    int col = cs * 16 + (lane & 15);
    int kbase = kc * 32 + ((lane >> 4) << 3);
    h8 hh, ll;
    #pragma unroll
    for (int j = 0; j < 8; j++) {
        int k = kbase + j;
        float v = 0.f;
        int kr = (k < split) ? k : (k - gap);
        bool valid = (k < split) ? (k < Kin) : (k >= split + gap && kr < Kin);
        if (valid) {
            v = W[(size_t)kr * N + col];
            if (scale) v *= scale[kr];
        }
        h16 hi = f2h(v);
        hh[j] = hi;
        ll[j] = f2h(v - h2f(hi));
    }
    *(h8*)(WtH + (size_t)u * 8) = hh;
    *(h8*)(WtL + (size_t)u * 8) = ll;
}

// ---------------- bias2 = bias + shift @ W (wave per output) ----------------
__global__ void k_bias2(const float* __restrict__ W, const float* __restrict__ bias,
                        const float* __restrict__ shift, float* __restrict__ bias2,
                        int N, int Kin) {
    int n = blockIdx.x;
    int lane = threadIdx.x;
    float acc = 0.f;
    if (shift) {
        for (int k = lane; k < Kin; k += 64)
            acc = fmaf(shift[k], W[(size_t)k * N + n], acc);
    }
    for (int off = 32; off; off >>= 1) acc += __shfl_down(acc, off, 64);
    if (lane == 0) bias2[n] = bias[n] + acc;
}

// ---------------- MFMA GEMM: 64 x (NS*64) tile; B direct-from-global (fragment order);
//                  A double-buffered in LDS; 1 barrier/ktile; deep prefetch ----------------
template <int NS, bool CONCAT, bool POOL>
__global__ __launch_bounds__(256) void k_gemm(
    const h16* __restrict__ A, int lda, int KA,
    const h16* __restrict__ WtH, const h16* __restrict__ WtL, int Kpad,
    const float* __restrict__ bias2, int Nc,
    const h16* __restrict__ Gp, const int* __restrict__ batch,
    int M,
    h16* __restrict__ C,
    float* __restrict__ ssum, float* __restrict__ ssq,
    unsigned* __restrict__ mx, unsigned* __restrict__ mn) {
    __shared__ h16 As[2][2048];

    const int t = threadIdx.x;
    const int row0 = blockIdx.y * 64;
    const int col0 = blockIdx.x * (NS * 64);
    const int w = t >> 6, lane = t & 63, quad = lane >> 4, m = lane & 15;
    const int nkc = Kpad >> 5;

    f4 acc[NS][4];
    #pragma unroll
    for (int sp = 0; sp < NS; sp++)
        #pragma unroll
        for (int i = 0; i < 4; i++)
            #pragma unroll
            for (int j = 0; j < 4; j++) acc[sp][i][j] = 0.f;

    const int rl = ((t >> 6) << 4) | (t & 15);
    const int ch = (t >> 4) & 3;
    const int r = row0 + rl;
    int bg = 0;
    if (CONCAT) bg = (r < M) ? batch[r] : 0;
    const h16* Arow = A + (size_t)r * lda;
    const int st = t * 8;
    const int fidx = quad * 128 + m * 8;
    size_t bo[NS];
    #pragma unroll
    for (int sp = 0; sp < NS; sp++)
        bo[sp] = ((size_t)((col0 >> 4) + w + 4 * sp) * nkc * 64 + lane) * 8;

    auto LOADA = [&](int k0, h8& av) {
        int k = k0 + ch * 8;
        #pragma unroll
        for (int j = 0; j < 8; j++) av[j] = (h16)0.f;
        if (r < M) {
            if (!CONCAT) {
                if (k < KA) av = *(const h8*)(Arow + k);
            } else {
                if (k < LOCP) av = *(const h8*)(Arow + k);
                else if (k < KA) av = *(const h8*)(Gp + (size_t)bg * 1024 + (k - LOCP));
            }
        }
    };

    h8 a0, a1;
    h8 cbh[NS], cbl[NS], nbh[NS], nbl[NS];
    LOADA(0, a0);
    #pragma unroll
    for (int sp = 0; sp < NS; sp++) {
        cbh[sp] = *(const h8*)(WtH + bo[sp]);
        cbl[sp] = *(const h8*)(WtL + bo[sp]);
    }

    for (int kt = 0; kt < nkc; kt++) {
        h16* buf = (h16*)As[kt & 1];
        *(h8*)(buf + st) = a0;
        if (kt + 1 < nkc) {
            LOADA((kt + 1) * 32, a1);
            #pragma unroll
            for (int sp = 0; sp < NS; sp++) {
                size_t o = bo[sp] + (size_t)(kt + 1) * 512;
                nbh[sp] = *(const h8*)(WtH + o);
                nbl[sp] = *(const h8*)(WtL + o);
            }
        }
        __syncthreads();
        #pragma unroll
        for (int rt = 0; rt < 4; rt++) {
            h8 af = *(const h8*)(buf + rt * 512 + fidx);
            #pragma unroll
            for (int sp = 0; sp < NS; sp++) {
                acc[sp][rt] = __builtin_amdgcn_mfma_f32_16x16x32_f16(af, cbh[sp], acc[sp][rt], 0, 0, 0);
                acc[sp][rt] = __builtin_amdgcn_mfma_f32_16x16x32_f16(af, cbl[sp], acc[sp][rt], 0, 0, 0);
            }
        }
        a0 = a1;
        #pragma unroll
        for (int sp = 0; sp < NS; sp++) { cbh[sp] = nbh[sp]; cbl[sp] = nbl[sp]; }
    }

    bool unig = true; int gblk = 0;
    if (POOL) {
        gblk = batch[min(row0, M - 1)];
        unig = (batch[min(row0 + 63, M - 1)] == gblk);
    }

    #pragma unroll
    for (int sp = 0; sp < NS; sp++) {
        const int col = col0 + (w + 4 * sp) * 16 + m;
        const float bi = bias2[col];
        float sv = 0.f, qv = 0.f;
        unsigned um = 0u, un = 0x7f800000u;
        #pragma unroll
        for (int rt = 0; rt < 4; rt++) {
            #pragma unroll
            for (int rg = 0; rg < 4; rg++) {
                int rr = row0 + rt * 16 + quad * 4 + rg;
                if (rr < M) {
                    float y = acc[sp][rt][rg] + bi;
                    y = y > 0.f ? y : 0.f;
                    if (!POOL) C[(size_t)rr * Nc + col] = f2h(y);
                    sv += y; qv += y * y;
                    if (POOL) {
                        unsigned ub = __float_as_uint(y);
                        if (unig) { um = max(um, ub); un = min(un, ub); }
                        else {
                            int gg = batch[rr];
                            atomicMax(&mx[gg * 1024 + col], ub);
                            atomicMin(&mn[gg * 1024 + col], ub);
                        }
                    }
                }
            }
        }
        sv += __shfl_xor(sv, 16, 64); sv += __shfl_xor(sv, 32, 64);
        qv += __shfl_xor(qv, 16, 64); qv += __shfl_xor(qv, 32, 64);
        if (POOL && unig) {
            um = max(um, (unsigned)__shfl_xor((int)um, 16, 64));
            um = max(um, (unsigned)__shfl_xor((int)um, 32, 64));
            un = min(un, (unsigned)__shfl_xor((int)un, 16, 64));
            un = min(un, (unsigned)__shfl_xor((int)un, 32, 64));
        }
        if (quad == 0) {
            int slot = blockIdx.y & 63;
            atomicAdd(&ssum[slot * Nc + col], sv);
            atomicAdd(&ssq[slot * Nc + col], qv);
            if (POOL && unig) {
                atomicMax(&mx[gblk * 1024 + col], um);
                atomicMin(&mn[gblk * 1024 + col], un);
            }
        }
    }
}

// ---------------- pooling helpers ----------------
__global__ void k_init_minmax(unsigned* __restrict__ mx, unsigned* __restrict__ mn) {
    int i = blockIdx.x * 256 + threadIdx.x;
    if (i < NGRAPH * 1024) { mx[i] = 0u; mn[i] = 0x7f800000u; }
}

__global__ void k_pool_fin(const unsigned* __restrict__ mx, const unsigned* __restrict__ mn,
                           const float* __restrict__ scale, const float* __restrict__ shift,
                           h16* __restrict__ pooled_h) {
    int i = blockIdx.x * 256 + threadIdx.x;
    if (i >= NGRAPH * 1024) return;
    int c = i & 1023;
    float sc = scale[c], sh = shift[c];
    float vmax = __uint_as_float(mx[i]);
    float vmin = __uint_as_float(mn[i]);
    float v = sc > 0.f ? fmaf(sc, vmax, sh) : fmaf(sc, vmin, sh);
    pooled_h[i] = f2h(v);
}

// ---------------- final fold + output ----------------
__global__ void k_fold(const float* __restrict__ scale, const float* __restrict__ shift,
                       const float* __restrict__ ow, const float* __restrict__ ob,
                       float* __restrict__ wprime, float* __restrict__ bprime) {
    int c = threadIdx.x;  // 128
    float w = ow[c];
    wprime[c] = scale[c] * w;
    float v = shift[c] * w;
    for (int off = 32; off; off >>= 1) v += __shfl_down(v, off, 64);
    __shared__ float l[2];
    if ((c & 63) == 0) l[c >> 6] = v;
    __syncthreads();
    if (c == 0) bprime[0] = l[0] + l[1] + ob[0];
}

__global__ void k_out(const h16* __restrict__ p3, const float* __restrict__ wprime,
                      const float* __restrict__ bprime, float* __restrict__ out) {
    int n = blockIdx.x * 256 + threadIdx.x;
    if (n >= NN) return;
    const h16* r = p3 + (size_t)n * 128;
    float acc = bprime[0];
    #pragma unroll
    for (int q = 0; q < 128; q++) acc = fmaf(h2f(r[q]), wprime[q], acc);
    out[n] = acc;
}

extern "C" void kernel_launch(void* const* d_in, const int* in_sizes, int n_in,
                              void* d_out, int out_size, void* d_ws, size_t ws_size,
                              hipStream_t stream) {
    const float* pos = (const float*)d_in[0];
    const float* nrm = (const float*)d_in[1];
    const float* cur = (const float*)d_in[2];
    const int* ei = (const int*)d_in[3];
    const int* src = ei;
    const int* dst = ei + NE;
    const int* batch = (const int*)d_in[4];
    const float* w_nb0 = (const float*)d_in[5];
    const float* b_nb0 = (const float*)d_in[6];
    const float* w_rt0 = (const float*)d_in[7];
    const float* w_nb = (const float*)d_in[8];
    const float* b_nb = (const float*)d_in[9];
    const float* w_rt = (const float*)d_in[10];
    const float* bn_g = (const float*)d_in[11];
    const float* bn_b = (const float*)d_in[12];
    const float* g_w1 = (const float*)d_in[13];
    const float* g_b1 = (const float*)d_in[14];
    const float* g_g1 = (const float*)d_in[15];
    const float* g_be1 = (const float*)d_in[16];
    const float* g_w2 = (const float*)d_in[17];
    const float* g_b2 = (const float*)d_in[18];
    const float* g_g2 = (const float*)d_in[19];
    const float* g_be2 = (const float*)d_in[20];
    const float* g_w3 = (const float*)d_in[21];
    const float* g_b3 = (const float*)d_in[22];
    const float* g_g3 = (const float*)d_in[23];
    const float* g_be3 = (const float*)d_in[24];
    const float* p_w1 = (const float*)d_in[25];
    const float* p_b1 = (const float*)d_in[26];
    const float* p_g1 = (const float*)d_in[27];
    const float* p_be1 = (const float*)d_in[28];
    const float* p_w2 = (const float*)d_in[29];
    const float* p_b2 = (const float*)d_in[30];
    const float* p_g2 = (const float*)d_in[31];
    const float* p_be2 = (const float*)d_in[32];
    const float* p_w3 = (const float*)d_in[33];
    const float* p_b3 = (const float*)d_in[34];
    const float* p_g3 = (const float*)d_in[35];
    const float* p_be3 = (const float*)d_in[36];
    const float* out_w = (const float*)d_in[37];
    const float* out_b = (const float*)d_in[38];
    float* out = (float*)d_out;

    char* base = (char*)d_ws;
    size_t off = 0;
    auto alloc = [&](size_t bytes) -> void* {
        void* p = base + off;
        off = (off + bytes + 255) & ~(size_t)255;
        return p;
    };

    // --- overlay arena region (dead after phase 1) doubles as WtH arena (phase >= 2) ---
    int* cnt = (int*)alloc((size_t)NN * 4);
    int* cursor = (int*)alloc((size_t)NN * 4);
    float* sg_sum = (float*)alloc(DEPTH * 64 * 16 * 4);   // per-layer slices
    float* sg_sq = (float*)alloc(DEPTH * 64 * 16 * 4);
    int* row_start = (int*)alloc((size_t)(NN + 1) * 4);
    float* inv_cnt = (float*)alloc((size_t)NN * 4);
    int* bsum = (int*)alloc(512 * 4);
    h16* wt_arena = (h16*)base;                        // overlays the arrays above
    h16* WtH_g1 = wt_arena + 0;        // 256*192
    h16* WtH_g2 = wt_arena + 49152;    // 512*256
    h16* WtH_g3 = wt_arena + 180224;   // 1024*512  (ends 704512)
    h16* WtH_p1 = wt_arena + 0;        // 512*1216
    h16* WtH_p2 = wt_arena + 622592;   // 256*512
    h16* WtH_p3 = wt_arena + 753664;   // 128*256   (ends 786432 halfs; fits)

    // --- GEMM stat slots (live phases 2-3; self-cleaned by bn_fin) ---
    float* gs_sum = (float*)alloc(64 * 1024 * 4);
    float* gs_sq = (float*)alloc(64 * 1024 * 4);
    size_t zend = off;  // memset [0, zend)

    // --- WtL arena (fully written by k_wt) ---
    h16* wtlo_arena = (h16*)alloc((size_t)786432 * 2);
    h16* WtL_g1 = wtlo_arena + 0;
    h16* WtL_g2 = wtlo_arena + 49152;
    h16* WtL_g3 = wtlo_arena + 180224;
    h16* WtL_p1 = wtlo_arena + 0;
    h16* WtL_p2 = wtlo_arena + 622592;
    h16* WtL_p3 = wtlo_arena + 753664;

    // --- small persistent ---
    const int CS[6] = {256, 512, 1024, 512, 256, 128};
    float* sc_arr[6];
    float* sh_arr[6];
    for (int i = 0; i < 6; i++) {
        sc_arr[i] = (float*)alloc(CS[i] * 4);
        sh_arr[i] = (float*)alloc(CS[i] * 4);
    }
    unsigned* mx = (unsigned*)alloc(NGRAPH * 1024 * 4);
    unsigned* mn = (unsigned*)alloc(NGRAPH * 1024 * 4);
    h16* pooled_h = (h16*)alloc(NGRAPH * 1024 * 2);
    float* wprime = (float*)alloc(128 * 4);
    float* bprime = (float*)alloc(256);
    float* bias2 = (float*)alloc(2688 * 4);
    float* b2_g1 = bias2 + 0;
    float* b2_g2 = bias2 + 256;
    float* b2_g3 = bias2 + 768;
    float* b2_p1 = bias2 + 1792;
    float* b2_p2 = bias2 + 2304;
    float* b2_p3 = bias2 + 2560;

    // --- local (f16) ---
    h16* local = (h16*)alloc((size_t)NN * LOCP * 2);   // 35.2 MB

    // --- big overlay region O ---
    size_t O = off;
    float* x_cur = (float*)(base + O);                       // 6.4 MB
    float* h_buf = (float*)(base + O + (size_t)NN * 64);     // 6.4 MB
    int* csr = (int*)(base + O + (size_t)NN * 128);          // 12.8 MB (dead before g1)
    h16* g1b = (h16*)(base + O);                             // 51.2 MB
    h16* g2b = (h16*)(base + O + (size_t)NN * 512);          // 102.4 MB
    h16* p1b = g2b;
    h16* p2b = g1b;
    h16* p3b = local;
    size_t need = O + (size_t)NN * 512 + (size_t)NN * 1024;

    if (need > ws_size) return;

    const int NB = (NN + 255) / 256;  // 391
    hipMemsetAsync(base, 0, zend, stream);
    k_init_minmax<<<32, 256, 0, stream>>>(mx, mn);
    k_count<<<NE / 256, 256, 0, stream>>>(dst, cnt);
    k_scan1<<<NB, 256, 0, stream>>>(cnt, row_start, bsum);
    k_scan2<<<1, 512, 0, stream>>>(bsum, NB);
    k_scan3<<<NB, 256, 0, stream>>>(cnt, row_start, bsum, inv_cnt);
    k_fill<<<NE / 256, 256, 0, stream>>>(src, dst, row_start, cursor, csr);
    k_build_x0<<<(NN + 255) / 256, 256, 0, stream>>>(pos, nrm, cur, x_cur, local);

    for (int i = 0; i < DEPTH; i++) {
        const float* wn = (i == 0) ? w_nb0 : (w_nb + (size_t)(i - 1) * 256);
        const float* bnb = (i == 0) ? b_nb0 : (b_nb + (size_t)(i - 1) * 16);
        const float* wr = (i == 0) ? w_rt0 : (w_rt + (size_t)(i - 1) * 256);
        int kin = (i == 0) ? 7 : 16;
        float* ls = sg_sum + i * 1024;
        float* lq = sg_sq + i * 1024;
        k_sage<<<(NN + 63) / 64, 256, 0, stream>>>(x_cur, row_start, csr, inv_cnt,
                                                   wn, bnb, wr, kin, h_buf, ls, lq);
        k_apply<<<NN * 16 / 256, 256, 0, stream>>>(h_buf, ls, lq, bn_g + i * 16, bn_b + i * 16,
                                                   x_cur, local, i * 16);
    }

    const int GRY = (NN + 63) / 64;  // 1563

    // g1: local[176pad->192] -> 256
    k_wt<<<(256 * 192 / 8 + 255) / 256, 256, 0, stream>>>(g_w1, nullptr, WtH_g1, WtL_g1, 256, 167, 192, 167, 0);
    k_bias2<<<256, 64, 0, stream>>>(g_w1, g_b1, nullptr, b2_g1, 256, 167);
    k_gemm<4, false, false><<<dim3(1, GRY), 256, 0, stream>>>(
        local, LOCP, LOCP, WtH_g1, WtL_g1, 192, b2_g1, 256, nullptr, batch, NN,
        g1b, gs_sum, gs_sq, nullptr, nullptr);
    k_bn_fin<<<1, 256, 0, stream>>>(gs_sum, gs_sq, g_g1, g_be1, (float)NN, 256, sc_arr[0], sh_arr[0]);

    // g2: 256 -> 512 (affine folded)
    k_wt<<<(512 * 256 / 8 + 255) / 256, 256, 0, stream>>>(g_w2, sc_arr[0], WtH_g2, WtL_g2, 512, 256, 256, 256, 0);
    k_bias2<<<512, 64, 0, stream>>>(g_w2, g_b2, sh_arr[0], b2_g2, 512, 256);
    k_gemm<4, false, false><<<dim3(2, GRY), 256, 0, stream>>>(
        g1b, 256, 256, WtH_g2, WtL_g2, 256, b2_g2, 512, nullptr, batch, NN,
        g2b, gs_sum, gs_sq, nullptr, nullptr);
    k_bn_fin<<<2, 256, 0, stream>>>(gs_sum, gs_sq, g_g2, g_be2, (float)NN, 512, sc_arr[1], sh_arr[1]);

    // g3: 512 -> 1024, fused pooling
    k_wt<<<(1024 * 512 / 8 + 255) / 256, 256, 0, stream>>>(g_w3, sc_arr[1], WtH_g3, WtL_g3, 1024, 512, 512, 512, 0);
    k_bias2<<<1024, 64, 0, stream>>>(g_w3, g_b3, sh_arr[1], b2_g3, 1024, 512);
    k_gemm<4, false, true><<<dim3(4, GRY), 256, 0, stream>>>(
        g2b, 512, 512, WtH_g3, WtL_g3, 512, b2_g3, 1024, nullptr, batch, NN,
        nullptr, gs_sum, gs_sq, mx, mn);
    k_bn_fin<<<4, 256, 0, stream>>>(gs_sum, gs_sq, g_g3, g_be3, (float)NN, 1024, sc_arr[2], sh_arr[2]);
    k_pool_fin<<<32, 256, 0, stream>>>(mx, mn, sc_arr[2], sh_arr[2], pooled_h);

    // p1: concat(local[176], pooled[1024]) -> 512
    k_wt<<<(512 * 1216 / 8 + 255) / 256, 256, 0, stream>>>(p_w1, nullptr, WtH_p1, WtL_p1, 512, 1191, 1216, 167, 9);
    k_bias2<<<512, 64, 0, stream>>>(p_w1, p_b1, nullptr, b2_p1, 512, 1191);
    k_gemm<4, true, false><<<dim3(2, GRY), 256, 0, stream>>>(
        local, LOCP, 1200, WtH_p1, WtL_p1, 1216, b2_p1, 512, pooled_h, batch, NN,
        p1b, gs_sum, gs_sq, nullptr, nullptr);
    k_bn_fin<<<2, 256, 0, stream>>>(gs_sum, gs_sq, p_g1, p_be1, (float)NN, 512, sc_arr[3], sh_arr[3]);

    // p2: 512 -> 256
    k_wt<<<(256 * 512 / 8 + 255) / 256, 256, 0, stream>>>(p_w2, sc_arr[3], WtH_p2, WtL_p2, 256, 512, 512, 512, 0);
    k_bias2<<<256, 64, 0, stream>>>(p_w2, p_b2, sh_arr[3], b2_p2, 256, 512);
    k_gemm<4, false, false><<<dim3(1, GRY), 256, 0, stream>>>(
        p1b, 512, 512, WtH_p2, WtL_p2, 512, b2_p2, 256, nullptr, batch, NN,
        p2b, gs_sum, gs_sq, nullptr, nullptr);
    k_bn_fin<<<1, 256, 0, stream>>>(gs_sum, gs_sq, p_g2, p_be2, (float)NN, 256, sc_arr[4], sh_arr[4]);

    // p3: 256 -> 128
    k_wt<<<(128 * 256 / 8 + 255) / 256, 256, 0, stream>>>(p_w3, sc_arr[4], WtH_p3, WtL_p3, 128, 256, 256, 256, 0);
    k_bias2<<<128, 64, 0, stream>>>(p_w3, p_b3, sh_arr[4], b2_p3, 128, 256);
    k_gemm<2, false, false><<<dim3(1, GRY), 256, 0, stream>>>(
        p2b, 256, 256, WtH_p3, WtL_p3, 256, b2_p3, 128, nullptr, batch, NN,
        p3b, gs_sum, gs_sq, nullptr, nullptr);
    k_bn_fin<<<1, 128, 0, stream>>>(gs_sum, gs_sq, p_g3, p_be3, (float)NN, 128, sc_arr[5], sh_arr[5]);

    k_fold<<<1, 128, 0, stream>>>(sc_arr[5], sh_arr[5], out_w, out_b, wprime, bprime);
    k_out<<<(NN + 255) / 256, 256, 0, stream>>>(p3b, wprime, bprime, out);
}

// Round 14
// 1961.298 us; speedup vs baseline: 1.0918x; 1.0918x over previous
//
#include <hip/hip_runtime.h>
#include <math.h>

#define NN 100000
#define NE 3200000
#define NGRAPH 8
#define DEPTH 10
#define LOCC 167
#define LOCP 176
#define BNEPS 1e-5f

typedef _Float16 h16;
typedef _Float16 h8 __attribute__((ext_vector_type(8)));
typedef float f4 __attribute__((ext_vector_type(4)));

__device__ __forceinline__ float h2f(h16 v) { return (float)v; }
__device__ __forceinline__ h16 f2h(float v) { return (h16)v; }

// ---------------- CSR build ----------------
__global__ void k_count(const int* __restrict__ dst, int* __restrict__ cnt) {
    int e = blockIdx.x * 256 + threadIdx.x;
    atomicAdd(&cnt[dst[e]], 1);
}

__global__ __launch_bounds__(256) void k_scan1(const int* __restrict__ cnt,
                                               int* __restrict__ row_start,
                                               int* __restrict__ bsum) {
    int i = blockIdx.x * 256 + threadIdx.x;
    int lane = threadIdx.x & 63, wid = threadIdx.x >> 6;
    int v = (i < NN) ? cnt[i] : 0;
    int orig = v;
    #pragma unroll
    for (int off = 1; off < 64; off <<= 1) {
        int u = __shfl_up(v, off, 64);
        if (lane >= off) v += u;
    }
    __shared__ int ws[4];
    if (lane == 63) ws[wid] = v;
    __syncthreads();
    int add = 0;
    for (int w = 0; w < wid; w++) add += ws[w];
    v += add;
    if (i < NN) row_start[i] = v - orig;
    if (threadIdx.x == 255) bsum[blockIdx.x] = v;
}

__global__ __launch_bounds__(512) void k_scan2(int* __restrict__ bsum, int nb) {
    int t = threadIdx.x, lane = t & 63, wid = t >> 6;
    int v = (t < nb) ? bsum[t] : 0;
    int orig = v;
    #pragma unroll
    for (int off = 1; off < 64; off <<= 1) {
        int u = __shfl_up(v, off, 64);
        if (lane >= off) v += u;
    }
    __shared__ int ws[8];
    if (lane == 63) ws[wid] = v;
    __syncthreads();
    int add = 0;
    for (int w = 0; w < wid; w++) add += ws[w];
    v += add;
    if (t < nb) bsum[t] = v - orig;
}

__global__ void k_scan3(const int* __restrict__ cnt, int* __restrict__ row_start,
                        const int* __restrict__ bsum, float* __restrict__ inv_cnt) {
    int i = blockIdx.x * 256 + threadIdx.x;
    if (i < NN) {
        row_start[i] += bsum[blockIdx.x];
        inv_cnt[i] = 1.0f / fmaxf((float)cnt[i], 1.0f);
    }
    if (i == 0) row_start[NN] = NE;
}

__global__ void k_fill(const int* __restrict__ src, const int* __restrict__ dst,
                       const int* __restrict__ row_start, int* __restrict__ cursor,
                       int* __restrict__ csr) {
    int e = blockIdx.x * 256 + threadIdx.x;
    int d = dst[e];
    int o = atomicAdd(&cursor[d], 1);
    csr[row_start[d] + o] = src[e];
}

// ---------------- input build ----------------
__global__ void k_build_x0(const float* __restrict__ pos, const float* __restrict__ nrm,
                           const float* __restrict__ cur, float* __restrict__ x,
                           h16* __restrict__ local) {
    int n = blockIdx.x * 256 + threadIdx.x;
    if (n >= NN) return;
    float v[7];
    v[0] = pos[n * 3 + 0]; v[1] = pos[n * 3 + 1]; v[2] = pos[n * 3 + 2];
    v[3] = nrm[n * 3 + 0]; v[4] = nrm[n * 3 + 1]; v[5] = nrm[n * 3 + 2];
    v[6] = cur[n];
    float* xr = x + (size_t)n * 16;
    #pragma unroll
    for (int c = 0; c < 7; c++) xr[c] = v[c];
    #pragma unroll
    for (int c = 7; c < 16; c++) xr[c] = 0.f;
    h16* lr = local + (size_t)n * LOCP;
    #pragma unroll
    for (int c = 0; c < 7; c++) lr[160 + c] = f2h(v[c]);
    #pragma unroll
    for (int c = LOCC; c < LOCP; c++) lr[c] = f2h(0.f);
}

// ---------------- SAGE: 4 lanes/node, 16 nodes/wave, float4 gathers, 8-deep ----------------
__global__ __launch_bounds__(256) void k_sage(
    const float* __restrict__ x, const int* __restrict__ row_start,
    const int* __restrict__ csr, const float* __restrict__ inv_cnt,
    const float* __restrict__ w_nb, const float* __restrict__ b_nb,
    const float* __restrict__ w_rt, int kin,
    float* __restrict__ h_out, float* __restrict__ ssum, float* __restrict__ ssq) {
    const float4* x4 = (const float4*)x;
    int t = threadIdx.x, lane = t & 63, wid = t >> 6;
    int n = blockIdx.x * 64 + wid * 16 + (lane >> 2);
    int q = lane & 3;
    bool valid = n < NN;
    int s = 0, e = 0;
    if (valid) { s = row_start[n]; e = row_start[n + 1]; }
    float ax = 0.f, ay = 0.f, az = 0.f, aw = 0.f;
    float bx = 0.f, by = 0.f, bz = 0.f, bw = 0.f;
    int j = s;
    for (; j + 7 < e; j += 8) {
        int a0 = csr[j], a1 = csr[j + 1], a2 = csr[j + 2], a3 = csr[j + 3];
        int a4 = csr[j + 4], a5 = csr[j + 5], a6 = csr[j + 6], a7 = csr[j + 7];
        float4 v0 = x4[a0 * 4 + q];
        float4 v1 = x4[a1 * 4 + q];
        float4 v2 = x4[a2 * 4 + q];
        float4 v3 = x4[a3 * 4 + q];
        float4 v4 = x4[a4 * 4 + q];
        float4 v5 = x4[a5 * 4 + q];
        float4 v6 = x4[a6 * 4 + q];
        float4 v7 = x4[a7 * 4 + q];
        ax += (v0.x + v1.x) + (v2.x + v3.x);
        ay += (v0.y + v1.y) + (v2.y + v3.y);
        az += (v0.z + v1.z) + (v2.z + v3.z);
        aw += (v0.w + v1.w) + (v2.w + v3.w);
        bx += (v4.x + v5.x) + (v6.x + v7.x);
        by += (v4.y + v5.y) + (v6.y + v7.y);
        bz += (v4.z + v5.z) + (v6.z + v7.z);
        bw += (v4.w + v5.w) + (v6.w + v7.w);
    }
    for (; j < e; j++) {
        float4 v = x4[csr[j] * 4 + q];
        ax += v.x; ay += v.y; az += v.z; aw += v.w;
    }
    ax += bx; ay += by; az += bz; aw += bw;
    float ic = valid ? inv_cnt[n] : 0.f;
    float agg[4] = {ax * ic, ay * ic, az * ic, aw * ic};
    float xn[4] = {0.f, 0.f, 0.f, 0.f};
    if (valid) {
        float4 v = x4[n * 4 + q];
        xn[0] = v.x; xn[1] = v.y; xn[2] = v.z; xn[3] = v.w;
    }
    float hc0 = 0.f, hc1 = 0.f, hc2 = 0.f, hc3 = 0.f;
    #pragma unroll
    for (int r = 0; r < 4; r++) {
        int kq = (q + r) & 3;
        int srcl = (lane & 60) | kq;
        float av[4], xv[4];
        #pragma unroll
        for (int c = 0; c < 4; c++) {
            av[c] = __shfl(agg[c], srcl, 64);
            xv[c] = __shfl(xn[c], srcl, 64);
        }
        #pragma unroll
        for (int kk = 0; kk < 4; kk++) {
            int k = kq * 4 + kk;
            if (k < kin) {
                float4 wn4 = *(const float4*)&w_nb[k * 16 + 4 * q];
                float4 wr4 = *(const float4*)&w_rt[k * 16 + 4 * q];
                hc0 = fmaf(av[kk], wn4.x, hc0); hc0 = fmaf(xv[kk], wr4.x, hc0);
                hc1 = fmaf(av[kk], wn4.y, hc1); hc1 = fmaf(xv[kk], wr4.y, hc1);
                hc2 = fmaf(av[kk], wn4.z, hc2); hc2 = fmaf(xv[kk], wr4.z, hc2);
                hc3 = fmaf(av[kk], wn4.w, hc3); hc3 = fmaf(xv[kk], wr4.w, hc3);
            }
        }
    }
    float4 b4 = *(const float4*)&b_nb[4 * q];
    hc0 += b4.x; hc1 += b4.y; hc2 += b4.z; hc3 += b4.w;
    if (!valid) { hc0 = 0.f; hc1 = 0.f; hc2 = 0.f; hc3 = 0.f; }
    else {
        *(float4*)&h_out[(size_t)n * 16 + 4 * q] = make_float4(hc0, hc1, hc2, hc3);
    }
    float s0 = hc0, s1 = hc1, s2 = hc2, s3 = hc3;
    float q0 = hc0 * hc0, q1 = hc1 * hc1, q2 = hc2 * hc2, q3 = hc3 * hc3;
    #pragma unroll
    for (int off = 4; off < 64; off <<= 1) {
        s0 += __shfl_xor(s0, off, 64); s1 += __shfl_xor(s1, off, 64);
        s2 += __shfl_xor(s2, off, 64); s3 += __shfl_xor(s3, off, 64);
        q0 += __shfl_xor(q0, off, 64); q1 += __shfl_xor(q1, off, 64);
        q2 += __shfl_xor(q2, off, 64); q3 += __shfl_xor(q3, off, 64);
    }
    if (lane < 4) {
        int slot = blockIdx.x & 63;
        float* ps = &ssum[slot * 16 + 4 * lane];
        float* pq = &ssq[slot * 16 + 4 * lane];
        atomicAdd(ps + 0, s0); atomicAdd(ps + 1, s1);
        atomicAdd(ps + 2, s2); atomicAdd(ps + 3, s3);
        atomicAdd(pq + 0, q0); atomicAdd(pq + 1, q1);
        atomicAdd(pq + 2, q2); atomicAdd(pq + 3, q3);
    }
}

// ---------------- fused BN-finalize + apply (per-layer stat slice) ----------------
__global__ void k_apply(const float* __restrict__ h,
                        const float* __restrict__ ssum, const float* __restrict__ ssq,
                        const float* __restrict__ g, const float* __restrict__ b,
                        float* __restrict__ x, h16* __restrict__ local, int colbase) {
    __shared__ float sscale[16], sshift[16];
    int t = threadIdx.x;
    if (t < 16) {
        float s = 0.f, q = 0.f;
        for (int sl = 0; sl < 64; sl++) {
            s += ssum[sl * 16 + t];
            q += ssq[sl * 16 + t];
        }
        float mean = s / (float)NN;
        float var = q / (float)NN - mean * mean;
        var = var > 0.f ? var : 0.f;
        float sc = g[t] / sqrtf(var + BNEPS);
        sscale[t] = sc;
        sshift[t] = b[t] - mean * sc;
    }
    __syncthreads();
    int i = blockIdx.x * 256 + t;
    int n = i >> 4, c = i & 15;
    float v = fmaf(h[i], sscale[c], sshift[c]);
    float e = v > 0.f ? v : expm1f(v);
    x[i] = e;
    local[(size_t)n * LOCP + colbase + c] = f2h(e);
}

// ---------------- BN finalize (GEMM layers): 64-slot reduce + self-clean ----------------
__global__ void k_bn_fin(float* __restrict__ ssum, float* __restrict__ ssq,
                         const float* __restrict__ g, const float* __restrict__ b,
                         float M, int C, float* __restrict__ scale, float* __restrict__ shift) {
    int c = blockIdx.x * blockDim.x + threadIdx.x;
    if (c >= C) return;
    float s = 0.f, q = 0.f;
    for (int sl = 0; sl < 64; sl++) {
        s += ssum[sl * C + c]; ssum[sl * C + c] = 0.f;
        q += ssq[sl * C + c];  ssq[sl * C + c] = 0.f;
    }
    float mean = s / M;
    float var = q / M - mean * mean;
    var = var > 0.f ? var : 0.f;
    float sc = g[c] / sqrtf(var + BNEPS);
    scale[c] = sc;
    shift[c] = b[c] - mean * sc;
}

// ---------------- weight prep: fragment-order Wt (hi+lo) ----------------
__global__ void k_wt(const float* __restrict__ W, const float* __restrict__ scale,
                     h16* __restrict__ WtH, h16* __restrict__ WtL,
                     int N, int Kin, int Kpad, int split, int gap) {
    int u = blockIdx.x * 256 + threadIdx.x;
    int nkc = Kpad >> 5;
    int total = (N >> 4) * nkc * 64;
    if (u >= total) return;
    int lane = u & 63;
    int fc = u >> 6;
    int kc = fc % nkc;
    int cs = fc / nkc;
    int col = cs * 16 + (lane & 15);
    int kbase = kc * 32 + ((lane >> 4) << 3);
    h8 hh, ll;
    #pragma unroll
    for (int j = 0; j < 8; j++) {
        int k = kbase + j;
        float v = 0.f;
        int kr = (k < split) ? k : (k - gap);
        bool valid = (k < split) ? (k < Kin) : (k >= split + gap && kr < Kin);
        if (valid) {
            v = W[(size_t)kr * N + col];
            if (scale) v *= scale[kr];
        }
        h16 hi = f2h(v);
        hh[j] = hi;
        ll[j] = f2h(v - h2f(hi));
    }
    *(h8*)(WtH + (size_t)u * 8) = hh;
    *(h8*)(WtL + (size_t)u * 8) = ll;
}

// ---------------- bias2 = bias + shift @ W (wave per output) ----------------
__global__ void k_bias2(const float* __restrict__ W, const float* __restrict__ bias,
                        const float* __restrict__ shift, float* __restrict__ bias2,
                        int N, int Kin) {
    int n = blockIdx.x;
    int lane = threadIdx.x;
    float acc = 0.f;
    if (shift) {
        for (int k = lane; k < Kin; k += 64)
            acc = fmaf(shift[k], W[(size_t)k * N + n], acc);
    }
    for (int off = 32; off; off >>= 1) acc += __shfl_down(acc, off, 64);
    if (lane == 0) bias2[n] = bias[n] + acc;
}

// ---------------- MFMA GEMM: 64x(NS*64) tile; B direct-from-global (fragment order);
//                  A double-buffered LDS; XCD-aware block swizzle for A L2 reuse ----------------
template <int NS, bool CONCAT, bool POOL>
__global__ __launch_bounds__(256) void k_gemm(
    const h16* __restrict__ A, int lda, int KA,
    const h16* __restrict__ WtH, const h16* __restrict__ WtL, int Kpad,
    const float* __restrict__ bias2, int Nc,
    const h16* __restrict__ Gp, const int* __restrict__ batch,
    int M,
    h16* __restrict__ C,
    float* __restrict__ ssum, float* __restrict__ ssq,
    unsigned* __restrict__ mx, unsigned* __restrict__ mn) {
    __shared__ h16 As[2][2048];

    const int t = threadIdx.x;
    // XCD-aware swizzle: blocks with id % 8 == xcd cover the SAME 64-row A-block
    // across all column strips -> A-tile fetched into one XCD L2 once.
    int bx = blockIdx.x, by = blockIdx.y;
    {
        int nbx = gridDim.x;
        int id = by * nbx + bx;
        int gs = nbx * 8;
        int nfull = (gridDim.y >> 3) * gs;
        if (id < nfull) {
            int grp = id / gs;
            int w_ = id - grp * gs;
            bx = w_ >> 3;
            by = grp * 8 + (w_ & 7);
        }
    }
    const int row0 = by * 64;
    const int col0 = bx * (NS * 64);
    const int w = t >> 6, lane = t & 63, quad = lane >> 4, m = lane & 15;
    const int nkc = Kpad >> 5;

    f4 acc[NS][4];
    #pragma unroll
    for (int sp = 0; sp < NS; sp++)
        #pragma unroll
        for (int i = 0; i < 4; i++)
            #pragma unroll
            for (int j = 0; j < 4; j++) acc[sp][i][j] = 0.f;

    const int rl = ((t >> 6) << 4) | (t & 15);
    const int ch = (t >> 4) & 3;
    const int r = row0 + rl;
    int bg = 0;
    if (CONCAT) bg = (r < M) ? batch[r] : 0;
    const h16* Arow = A + (size_t)r * lda;
    const int st = t * 8;
    const int fidx = quad * 128 + m * 8;
    size_t bo[NS];
    #pragma unroll
    for (int sp = 0; sp < NS; sp++)
        bo[sp] = ((size_t)((col0 >> 4) + w + 4 * sp) * nkc * 64 + lane) * 8;

    auto LOADA = [&](int k0, h8& av) {
        int k = k0 + ch * 8;
        #pragma unroll
        for (int j = 0; j < 8; j++) av[j] = (h16)0.f;
        if (r < M) {
            if (!CONCAT) {
                if (k < KA) av = *(const h8*)(Arow + k);
            } else {
                if (k < LOCP) av = *(const h8*)(Arow + k);
                else if (k < KA) av = *(const h8*)(Gp + (size_t)bg * 1024 + (k - LOCP));
            }
        }
    };

    h8 a0, a1;
    h8 cbh[NS], cbl[NS], nbh[NS], nbl[NS];
    LOADA(0, a0);
    #pragma unroll
    for (int sp = 0; sp < NS; sp++) {
        cbh[sp] = *(const h8*)(WtH + bo[sp]);
        cbl[sp] = *(const h8*)(WtL + bo[sp]);
    }

    for (int kt = 0; kt < nkc; kt++) {
        h16* buf = (h16*)As[kt & 1];
        *(h8*)(buf + st) = a0;
        if (kt + 1 < nkc) {
            LOADA((kt + 1) * 32, a1);
            #pragma unroll
            for (int sp = 0; sp < NS; sp++) {
                size_t o = bo[sp] + (size_t)(kt + 1) * 512;
                nbh[sp] = *(const h8*)(WtH + o);
                nbl[sp] = *(const h8*)(WtL + o);
            }
        }
        __syncthreads();
        #pragma unroll
        for (int rt = 0; rt < 4; rt++) {
            h8 af = *(const h8*)(buf + rt * 512 + fidx);
            #pragma unroll
            for (int sp = 0; sp < NS; sp++) {
                acc[sp][rt] = __builtin_amdgcn_mfma_f32_16x16x32_f16(af, cbh[sp], acc[sp][rt], 0, 0, 0);
                acc[sp][rt] = __builtin_amdgcn_mfma_f32_16x16x32_f16(af, cbl[sp], acc[sp][rt], 0, 0, 0);
            }
        }
        a0 = a1;
        #pragma unroll
        for (int sp = 0; sp < NS; sp++) { cbh[sp] = nbh[sp]; cbl[sp] = nbl[sp]; }
    }

    bool unig = true; int gblk = 0;
    if (POOL) {
        gblk = batch[min(row0, M - 1)];
        unig = (batch[min(row0 + 63, M - 1)] == gblk);
    }

    #pragma unroll
    for (int sp = 0; sp < NS; sp++) {
        const int col = col0 + (w + 4 * sp) * 16 + m;
        const float bi = bias2[col];
        float sv = 0.f, qv = 0.f;
        unsigned um = 0u, un = 0x7f800000u;
        #pragma unroll
        for (int rt = 0; rt < 4; rt++) {
            #pragma unroll
            for (int rg = 0; rg < 4; rg++) {
                int rr = row0 + rt * 16 + quad * 4 + rg;
                if (rr < M) {
                    float y = acc[sp][rt][rg] + bi;
                    y = y > 0.f ? y : 0.f;
                    if (!POOL) C[(size_t)rr * Nc + col] = f2h(y);
                    sv += y; qv += y * y;
                    if (POOL) {
                        unsigned ub = __float_as_uint(y);
                        if (unig) { um = max(um, ub); un = min(un, ub); }
                        else {
                            int gg = batch[rr];
                            atomicMax(&mx[gg * 1024 + col], ub);
                            atomicMin(&mn[gg * 1024 + col], ub);
                        }
                    }
                }
            }
        }
        sv += __shfl_xor(sv, 16, 64); sv += __shfl_xor(sv, 32, 64);
        qv += __shfl_xor(qv, 16, 64); qv += __shfl_xor(qv, 32, 64);
        if (POOL && unig) {
            um = max(um, (unsigned)__shfl_xor((int)um, 16, 64));
            um = max(um, (unsigned)__shfl_xor((int)um, 32, 64));
            un = min(un, (unsigned)__shfl_xor((int)un, 16, 64));
            un = min(un, (unsigned)__shfl_xor((int)un, 32, 64));
        }
        if (quad == 0) {
            int slot = by & 63;
            atomicAdd(&ssum[slot * Nc + col], sv);
            atomicAdd(&ssq[slot * Nc + col], qv);
            if (POOL && unig) {
                atomicMax(&mx[gblk * 1024 + col], um);
                atomicMin(&mn[gblk * 1024 + col], un);
            }
        }
    }
}

// ---------------- pooling helpers ----------------
__global__ void k_init_minmax(unsigned* __restrict__ mx, unsigned* __restrict__ mn) {
    int i = blockIdx.x * 256 + threadIdx.x;
    if (i < NGRAPH * 1024) { mx[i] = 0u; mn[i] = 0x7f800000u; }
}

__global__ void k_pool_fin(const unsigned* __restrict__ mx, const unsigned* __restrict__ mn,
                           const float* __restrict__ scale, const float* __restrict__ shift,
                           h16* __restrict__ pooled_h) {
    int i = blockIdx.x * 256 + threadIdx.x;
    if (i >= NGRAPH * 1024) return;
    int c = i & 1023;
    float sc = scale[c], sh = shift[c];
    float vmax = __uint_as_float(mx[i]);
    float vmin = __uint_as_float(mn[i]);
    float v = sc > 0.f ? fmaf(sc, vmax, sh) : fmaf(sc, vmin, sh);
    pooled_h[i] = f2h(v);
}

// ---------------- final fold + output ----------------
__global__ void k_fold(const float* __restrict__ scale, const float* __restrict__ shift,
                       const float* __restrict__ ow, const float* __restrict__ ob,
                       float* __restrict__ wprime, float* __restrict__ bprime) {
    int c = threadIdx.x;  // 128
    float w = ow[c];
    wprime[c] = scale[c] * w;
    float v = shift[c] * w;
    for (int off = 32; off; off >>= 1) v += __shfl_down(v, off, 64);
    __shared__ float l[2];
    if ((c & 63) == 0) l[c >> 6] = v;
    __syncthreads();
    if (c == 0) bprime[0] = l[0] + l[1] + ob[0];
}

__global__ void k_out(const h16* __restrict__ p3, const float* __restrict__ wprime,
                      const float* __restrict__ bprime, float* __restrict__ out) {
    int n = blockIdx.x * 256 + threadIdx.x;
    if (n >= NN) return;
    const h16* r = p3 + (size_t)n * 128;
    float acc = bprime[0];
    #pragma unroll
    for (int q = 0; q < 128; q++) acc = fmaf(h2f(r[q]), wprime[q], acc);
    out[n] = acc;
}

extern "C" void kernel_launch(void* const* d_in, const int* in_sizes, int n_in,
                              void* d_out, int out_size, void* d_ws, size_t ws_size,
                              hipStream_t stream) {
    const float* pos = (const float*)d_in[0];
    const float* nrm = (const float*)d_in[1];
    const float* cur = (const float*)d_in[2];
    const int* ei = (const int*)d_in[3];
    const int* src = ei;
    const int* dst = ei + NE;
    const int* batch = (const int*)d_in[4];
    const float* w_nb0 = (const float*)d_in[5];
    const float* b_nb0 = (const float*)d_in[6];
    const float* w_rt0 = (const float*)d_in[7];
    const float* w_nb = (const float*)d_in[8];
    const float* b_nb = (const float*)d_in[9];
    const float* w_rt = (const float*)d_in[10];
    const float* bn_g = (const float*)d_in[11];
    const float* bn_b = (const float*)d_in[12];
    const float* g_w1 = (const float*)d_in[13];
    const float* g_b1 = (const float*)d_in[14];
    const float* g_g1 = (const float*)d_in[15];
    const float* g_be1 = (const float*)d_in[16];
    const float* g_w2 = (const float*)d_in[17];
    const float* g_b2 = (const float*)d_in[18];
    const float* g_g2 = (const float*)d_in[19];
    const float* g_be2 = (const float*)d_in[20];
    const float* g_w3 = (const float*)d_in[21];
    const float* g_b3 = (const float*)d_in[22];
    const float* g_g3 = (const float*)d_in[23];
    const float* g_be3 = (const float*)d_in[24];
    const float* p_w1 = (const float*)d_in[25];
    const float* p_b1 = (const float*)d_in[26];
    const float* p_g1 = (const float*)d_in[27];
    const float* p_be1 = (const float*)d_in[28];
    const float* p_w2 = (const float*)d_in[29];
    const float* p_b2 = (const float*)d_in[30];
    const float* p_g2 = (const float*)d_in[31];
    const float* p_be2 = (const float*)d_in[32];
    const float* p_w3 = (const float*)d_in[33];
    const float* p_b3 = (const float*)d_in[34];
    const float* p_g3 = (const float*)d_in[35];
    const float* p_be3 = (const float*)d_in[36];
    const float* out_w = (const float*)d_in[37];
    const float* out_b = (const float*)d_in[38];
    float* out = (float*)d_out;

    char* base = (char*)d_ws;
    size_t off = 0;
    auto alloc = [&](size_t bytes) -> void* {
        void* p = base + off;
        off = (off + bytes + 255) & ~(size_t)255;
        return p;
    };

    // --- overlay arena region (dead after phase 1) doubles as WtH arena (phase >= 2) ---
    int* cnt = (int*)alloc((size_t)NN * 4);
    int* cursor = (int*)alloc((size_t)NN * 4);
    float* sg_sum = (float*)alloc(DEPTH * 64 * 16 * 4);   // per-layer slices
    float* sg_sq = (float*)alloc(DEPTH * 64 * 16 * 4);
    int* row_start = (int*)alloc((size_t)(NN + 1) * 4);
    float* inv_cnt = (float*)alloc((size_t)NN * 4);
    int* bsum = (int*)alloc(512 * 4);
    h16* wt_arena = (h16*)base;                        // overlays the arrays above
    h16* WtH_g1 = wt_arena + 0;        // 256*192
    h16* WtH_g2 = wt_arena + 49152;    // 512*256
    h16* WtH_g3 = wt_arena + 180224;   // 1024*512  (ends 704512)
    h16* WtH_p1 = wt_arena + 0;        // 512*1216
    h16* WtH_p2 = wt_arena + 622592;   // 256*512
    h16* WtH_p3 = wt_arena + 753664;   // 128*256   (ends 786432 halfs; fits)

    // --- GEMM stat slots (live phases 2-3; self-cleaned by bn_fin) ---
    float* gs_sum = (float*)alloc(64 * 1024 * 4);
    float* gs_sq = (float*)alloc(64 * 1024 * 4);
    size_t zend = off;  // memset [0, zend)

    // --- WtL arena (fully written by k_wt) ---
    h16* wtlo_arena = (h16*)alloc((size_t)786432 * 2);
    h16* WtL_g1 = wtlo_arena + 0;
    h16* WtL_g2 = wtlo_arena + 49152;
    h16* WtL_g3 = wtlo_arena + 180224;
    h16* WtL_p1 = wtlo_arena + 0;
    h16* WtL_p2 = wtlo_arena + 622592;
    h16* WtL_p3 = wtlo_arena + 753664;

    // --- small persistent ---
    const int CS[6] = {256, 512, 1024, 512, 256, 128};
    float* sc_arr[6];
    float* sh_arr[6];
    for (int i = 0; i < 6; i++) {
        sc_arr[i] = (float*)alloc(CS[i] * 4);
        sh_arr[i] = (float*)alloc(CS[i] * 4);
    }
    unsigned* mx = (unsigned*)alloc(NGRAPH * 1024 * 4);
    unsigned* mn = (unsigned*)alloc(NGRAPH * 1024 * 4);
    h16* pooled_h = (h16*)alloc(NGRAPH * 1024 * 2);
    float* wprime = (float*)alloc(128 * 4);
    float* bprime = (float*)alloc(256);
    float* bias2 = (float*)alloc(2688 * 4);
    float* b2_g1 = bias2 + 0;
    float* b2_g2 = bias2 + 256;
    float* b2_g3 = bias2 + 768;
    float* b2_p1 = bias2 + 1792;
    float* b2_p2 = bias2 + 2304;
    float* b2_p3 = bias2 + 2560;

    // --- local (f16) ---
    h16* local = (h16*)alloc((size_t)NN * LOCP * 2);   // 35.2 MB

    // --- big overlay region O ---
    size_t O = off;
    float* x_cur = (float*)(base + O);                       // 6.4 MB
    float* h_buf = (float*)(base + O + (size_t)NN * 64);     // 6.4 MB
    int* csr = (int*)(base + O + (size_t)NN * 128);          // 12.8 MB (dead before g1)
    h16* g1b = (h16*)(base + O);                             // 51.2 MB
    h16* g2b = (h16*)(base + O + (size_t)NN * 512);          // 102.4 MB
    h16* p1b = g2b;
    h16* p2b = g1b;
    h16* p3b = local;
    size_t need = O + (size_t)NN * 512 + (size_t)NN * 1024;

    if (need > ws_size) return;

    const int NB = (NN + 255) / 256;  // 391
    hipMemsetAsync(base, 0, zend, stream);
    k_init_minmax<<<32, 256, 0, stream>>>(mx, mn);
    k_count<<<NE / 256, 256, 0, stream>>>(dst, cnt);
    k_scan1<<<NB, 256, 0, stream>>>(cnt, row_start, bsum);
    k_scan2<<<1, 512, 0, stream>>>(bsum, NB);
    k_scan3<<<NB, 256, 0, stream>>>(cnt, row_start, bsum, inv_cnt);
    k_fill<<<NE / 256, 256, 0, stream>>>(src, dst, row_start, cursor, csr);
    k_build_x0<<<(NN + 255) / 256, 256, 0, stream>>>(pos, nrm, cur, x_cur, local);

    for (int i = 0; i < DEPTH; i++) {
        const float* wn = (i == 0) ? w_nb0 : (w_nb + (size_t)(i - 1) * 256);
        const float* bnb = (i == 0) ? b_nb0 : (b_nb + (size_t)(i - 1) * 16);
        const float* wr = (i == 0) ? w_rt0 : (w_rt + (size_t)(i - 1) * 256);
        int kin = (i == 0) ? 7 : 16;
        float* ls = sg_sum + i * 1024;
        float* lq = sg_sq + i * 1024;
        k_sage<<<(NN + 63) / 64, 256, 0, stream>>>(x_cur, row_start, csr, inv_cnt,
                                                   wn, bnb, wr, kin, h_buf, ls, lq);
        k_apply<<<NN * 16 / 256, 256, 0, stream>>>(h_buf, ls, lq, bn_g + i * 16, bn_b + i * 16,
                                                   x_cur, local, i * 16);
    }

    const int GRY = (NN + 63) / 64;  // 1563

    // g1: local[176pad->192] -> 256
    k_wt<<<(256 * 192 / 8 + 255) / 256, 256, 0, stream>>>(g_w1, nullptr, WtH_g1, WtL_g1, 256, 167, 192, 167, 0);
    k_bias2<<<256, 64, 0, stream>>>(g_w1, g_b1, nullptr, b2_g1, 256, 167);
    k_gemm<2, false, false><<<dim3(2, GRY), 256, 0, stream>>>(
        local, LOCP, LOCP, WtH_g1, WtL_g1, 192, b2_g1, 256, nullptr, batch, NN,
        g1b, gs_sum, gs_sq, nullptr, nullptr);
    k_bn_fin<<<1, 256, 0, stream>>>(gs_sum, gs_sq, g_g1, g_be1, (float)NN, 256, sc_arr[0], sh_arr[0]);

    // g2: 256 -> 512 (affine folded)
    k_wt<<<(512 * 256 / 8 + 255) / 256, 256, 0, stream>>>(g_w2, sc_arr[0], WtH_g2, WtL_g2, 512, 256, 256, 256, 0);
    k_bias2<<<512, 64, 0, stream>>>(g_w2, g_b2, sh_arr[0], b2_g2, 512, 256);
    k_gemm<2, false, false><<<dim3(4, GRY), 256, 0, stream>>>(
        g1b, 256, 256, WtH_g2, WtL_g2, 256, b2_g2, 512, nullptr, batch, NN,
        g2b, gs_sum, gs_sq, nullptr, nullptr);
    k_bn_fin<<<2, 256, 0, stream>>>(gs_sum, gs_sq, g_g2, g_be2, (float)NN, 512, sc_arr[1], sh_arr[1]);

    // g3: 512 -> 1024, fused pooling
    k_wt<<<(1024 * 512 / 8 + 255) / 256, 256, 0, stream>>>(g_w3, sc_arr[1], WtH_g3, WtL_g3, 1024, 512, 512, 512, 0);
    k_bias2<<<1024, 64, 0, stream>>>(g_w3, g_b3, sh_arr[1], b2_g3, 1024, 512);
    k_gemm<2, false, true><<<dim3(8, GRY), 256, 0, stream>>>(
        g2b, 512, 512, WtH_g3, WtL_g3, 512, b2_g3, 1024, nullptr, batch, NN,
        nullptr, gs_sum, gs_sq, mx, mn);
    k_bn_fin<<<4, 256, 0, stream>>>(gs_sum, gs_sq, g_g3, g_be3, (float)NN, 1024, sc_arr[2], sh_arr[2]);
    k_pool_fin<<<32, 256, 0, stream>>>(mx, mn, sc_arr[2], sh_arr[2], pooled_h);

    // p1: concat(local[176], pooled[1024]) -> 512
    k_wt<<<(512 * 1216 / 8 + 255) / 256, 256, 0, stream>>>(p_w1, nullptr, WtH_p1, WtL_p1, 512, 1191, 1216, 167, 9);
    k_bias2<<<512, 64, 0, stream>>>(p_w1, p_b1, nullptr, b2_p1, 512, 1191);
    k_gemm<2, true, false><<<dim3(4, GRY), 256, 0, stream>>>(
        local, LOCP, 1200, WtH_p1, WtL_p1, 1216, b2_p1, 512, pooled_h, batch, NN,
        p1b, gs_sum, gs_sq, nullptr, nullptr);
    k_bn_fin<<<2, 256, 0, stream>>>(gs_sum, gs_sq, p_g1, p_be1, (float)NN, 512, sc_arr[3], sh_arr[3]);

    // p2: 512 -> 256
    k_wt<<<(256 * 512 / 8 + 255) / 256, 256, 0, stream>>>(p_w2, sc_arr[3], WtH_p2, WtL_p2, 256, 512, 512, 512, 0);
    k_bias2<<<256, 64, 0, stream>>>(p_w2, p_b2, sh_arr[3], b2_p2, 256, 512);
    k_gemm<2, false, false><<<dim3(2, GRY), 256, 0, stream>>>(
        p1b, 512, 512, WtH_p2, WtL_p2, 512, b2_p2, 256, nullptr, batch, NN,
        p2b, gs_sum, gs_sq, nullptr, nullptr);
    k_bn_fin<<<1, 256, 0, stream>>>(gs_sum, gs_sq, p_g2, p_be2, (float)NN, 256, sc_arr[4], sh_arr[4]);

    // p3: 256 -> 128
    k_wt<<<(128 * 256 / 8 + 255) / 256, 256, 0, stream>>>(p_w3, sc_arr[4], WtH_p3, WtL_p3, 128, 256, 256, 256, 0);
    k_bias2<<<128, 64, 0, stream>>>(p_w3, p_b3, sh_arr[4], b2_p3, 128, 256);
    k_gemm<2, false, false><<<dim3(1, GRY), 256, 0, stream>>>(
        p2b, 256, 256, WtH_p3, WtL_p3, 256, b2_p3, 128, nullptr, batch, NN,
        p3b, gs_sum, gs_sq, nullptr, nullptr);
    k_bn_fin<<<1, 128, 0, stream>>>(gs_sum, gs_sq, p_g3, p_be3, (float)NN, 128, sc_arr[5], sh_arr[5]);

    k_fold<<<1, 128, 0, stream>>>(sc_arr[5], sh_arr[5], out_w, out_b, wprime, bprime);
    k_out<<<(NN + 255) / 256, 256, 0, stream>>>(p3b, wprime, bprime, out);
}

// Round 15
// 1851.752 us; speedup vs baseline: 1.1564x; 1.0592x over previous
//
#include <hip/hip_runtime.h>
#include <math.h>

#define NN 100000
#define NE 3200000
#define NGRAPH 8
#define DEPTH 10
#define LOCC 167
#define LOCP 192
#define BNEPS 1e-5f

typedef _Float16 h16;
typedef _Float16 h8 __attribute__((ext_vector_type(8)));
typedef float f4 __attribute__((ext_vector_type(4)));

__device__ __forceinline__ float h2f(h16 v) { return (float)v; }
__device__ __forceinline__ h16 f2h(float v) { return (h16)v; }

// ---------------- CSR build ----------------
__global__ void k_count(const int* __restrict__ dst, int* __restrict__ cnt) {
    int e = blockIdx.x * 256 + threadIdx.x;
    atomicAdd(&cnt[dst[e]], 1);
}

__global__ __launch_bounds__(256) void k_scan1(const int* __restrict__ cnt,
                                               int* __restrict__ row_start,
                                               int* __restrict__ bsum) {
    int i = blockIdx.x * 256 + threadIdx.x;
    int lane = threadIdx.x & 63, wid = threadIdx.x >> 6;
    int v = (i < NN) ? cnt[i] : 0;
    int orig = v;
    #pragma unroll
    for (int off = 1; off < 64; off <<= 1) {
        int u = __shfl_up(v, off, 64);
        if (lane >= off) v += u;
    }
    __shared__ int ws[4];
    if (lane == 63) ws[wid] = v;
    __syncthreads();
    int add = 0;
    for (int w = 0; w < wid; w++) add += ws[w];
    v += add;
    if (i < NN) row_start[i] = v - orig;
    if (threadIdx.x == 255) bsum[blockIdx.x] = v;
}

__global__ __launch_bounds__(512) void k_scan2(int* __restrict__ bsum, int nb) {
    int t = threadIdx.x, lane = t & 63, wid = t >> 6;
    int v = (t < nb) ? bsum[t] : 0;
    int orig = v;
    #pragma unroll
    for (int off = 1; off < 64; off <<= 1) {
        int u = __shfl_up(v, off, 64);
        if (lane >= off) v += u;
    }
    __shared__ int ws[8];
    if (lane == 63) ws[wid] = v;
    __syncthreads();
    int add = 0;
    for (int w = 0; w < wid; w++) add += ws[w];
    v += add;
    if (t < nb) bsum[t] = v - orig;
}

__global__ void k_scan3(const int* __restrict__ cnt, int* __restrict__ row_start,
                        const int* __restrict__ bsum, float* __restrict__ inv_cnt) {
    int i = blockIdx.x * 256 + threadIdx.x;
    if (i < NN) {
        row_start[i] += bsum[blockIdx.x];
        inv_cnt[i] = 1.0f / fmaxf((float)cnt[i], 1.0f);
    }
    if (i == 0) row_start[NN] = NE;
}

__global__ void k_fill(const int* __restrict__ src, const int* __restrict__ dst,
                       const int* __restrict__ row_start, int* __restrict__ cursor,
                       int* __restrict__ csr) {
    int e = blockIdx.x * 256 + threadIdx.x;
    int d = dst[e];
    int o = atomicAdd(&cursor[d], 1);
    csr[row_start[d] + o] = src[e];
}

// ---------------- input build ----------------
__global__ void k_build_x0(const float* __restrict__ pos, const float* __restrict__ nrm,
                           const float* __restrict__ cur, float* __restrict__ x,
                           h16* __restrict__ local) {
    int n = blockIdx.x * 256 + threadIdx.x;
    if (n >= NN) return;
    float v[7];
    v[0] = pos[n * 3 + 0]; v[1] = pos[n * 3 + 1]; v[2] = pos[n * 3 + 2];
    v[3] = nrm[n * 3 + 0]; v[4] = nrm[n * 3 + 1]; v[5] = nrm[n * 3 + 2];
    v[6] = cur[n];
    float* xr = x + (size_t)n * 16;
    #pragma unroll
    for (int c = 0; c < 7; c++) xr[c] = v[c];
    #pragma unroll
    for (int c = 7; c < 16; c++) xr[c] = 0.f;
    h16* lr = local + (size_t)n * LOCP;
    #pragma unroll
    for (int c = 0; c < 7; c++) lr[160 + c] = f2h(v[c]);
    #pragma unroll
    for (int c = LOCC; c < LOCP; c++) lr[c] = f2h(0.f);
}

// ---------------- SAGE: 4 lanes/node, 16 nodes/wave, float4 gathers, 8-deep ----------------
__global__ __launch_bounds__(256) void k_sage(
    const float* __restrict__ x, const int* __restrict__ row_start,
    const int* __restrict__ csr, const float* __restrict__ inv_cnt,
    const float* __restrict__ w_nb, const float* __restrict__ b_nb,
    const float* __restrict__ w_rt, int kin,
    float* __restrict__ h_out, float* __restrict__ ssum, float* __restrict__ ssq) {
    const float4* x4 = (const float4*)x;
    int t = threadIdx.x, lane = t & 63, wid = t >> 6;
    int n = blockIdx.x * 64 + wid * 16 + (lane >> 2);
    int q = lane & 3;
    bool valid = n < NN;
    int s = 0, e = 0;
    if (valid) { s = row_start[n]; e = row_start[n + 1]; }
    float ax = 0.f, ay = 0.f, az = 0.f, aw = 0.f;
    float bx = 0.f, by = 0.f, bz = 0.f, bw = 0.f;
    int j = s;
    for (; j + 7 < e; j += 8) {
        int a0 = csr[j], a1 = csr[j + 1], a2 = csr[j + 2], a3 = csr[j + 3];
        int a4 = csr[j + 4], a5 = csr[j + 5], a6 = csr[j + 6], a7 = csr[j + 7];
        float4 v0 = x4[a0 * 4 + q];
        float4 v1 = x4[a1 * 4 + q];
        float4 v2 = x4[a2 * 4 + q];
        float4 v3 = x4[a3 * 4 + q];
        float4 v4 = x4[a4 * 4 + q];
        float4 v5 = x4[a5 * 4 + q];
        float4 v6 = x4[a6 * 4 + q];
        float4 v7 = x4[a7 * 4 + q];
        ax += (v0.x + v1.x) + (v2.x + v3.x);
        ay += (v0.y + v1.y) + (v2.y + v3.y);
        az += (v0.z + v1.z) + (v2.z + v3.z);
        aw += (v0.w + v1.w) + (v2.w + v3.w);
        bx += (v4.x + v5.x) + (v6.x + v7.x);
        by += (v4.y + v5.y) + (v6.y + v7.y);
        bz += (v4.z + v5.z) + (v6.z + v7.z);
        bw += (v4.w + v5.w) + (v6.w + v7.w);
    }
    for (; j < e; j++) {
        float4 v = x4[csr[j] * 4 + q];
        ax += v.x; ay += v.y; az += v.z; aw += v.w;
    }
    ax += bx; ay += by; az += bz; aw += bw;
    float ic = valid ? inv_cnt[n] : 0.f;
    float agg[4] = {ax * ic, ay * ic, az * ic, aw * ic};
    float xn[4] = {0.f, 0.f, 0.f, 0.f};
    if (valid) {
        float4 v = x4[n * 4 + q];
        xn[0] = v.x; xn[1] = v.y; xn[2] = v.z; xn[3] = v.w;
    }
    float hc0 = 0.f, hc1 = 0.f, hc2 = 0.f, hc3 = 0.f;
    #pragma unroll
    for (int r = 0; r < 4; r++) {
        int kq = (q + r) & 3;
        int srcl = (lane & 60) | kq;
        float av[4], xv[4];
        #pragma unroll
        for (int c = 0; c < 4; c++) {
            av[c] = __shfl(agg[c], srcl, 64);
            xv[c] = __shfl(xn[c], srcl, 64);
        }
        #pragma unroll
        for (int kk = 0; kk < 4; kk++) {
            int k = kq * 4 + kk;
            if (k < kin) {
                float4 wn4 = *(const float4*)&w_nb[k * 16 + 4 * q];
                float4 wr4 = *(const float4*)&w_rt[k * 16 + 4 * q];
                hc0 = fmaf(av[kk], wn4.x, hc0); hc0 = fmaf(xv[kk], wr4.x, hc0);
                hc1 = fmaf(av[kk], wn4.y, hc1); hc1 = fmaf(xv[kk], wr4.y, hc1);
                hc2 = fmaf(av[kk], wn4.z, hc2); hc2 = fmaf(xv[kk], wr4.z, hc2);
                hc3 = fmaf(av[kk], wn4.w, hc3); hc3 = fmaf(xv[kk], wr4.w, hc3);
            }
        }
    }
    float4 b4 = *(const float4*)&b_nb[4 * q];
    hc0 += b4.x; hc1 += b4.y; hc2 += b4.z; hc3 += b4.w;
    if (!valid) { hc0 = 0.f; hc1 = 0.f; hc2 = 0.f; hc3 = 0.f; }
    else {
        *(float4*)&h_out[(size_t)n * 16 + 4 * q] = make_float4(hc0, hc1, hc2, hc3);
    }
    float s0 = hc0, s1 = hc1, s2 = hc2, s3 = hc3;
    float q0 = hc0 * hc0, q1 = hc1 * hc1, q2 = hc2 * hc2, q3 = hc3 * hc3;
    #pragma unroll
    for (int off = 4; off < 64; off <<= 1) {
        s0 += __shfl_xor(s0, off, 64); s1 += __shfl_xor(s1, off, 64);
        s2 += __shfl_xor(s2, off, 64); s3 += __shfl_xor(s3, off, 64);
        q0 += __shfl_xor(q0, off, 64); q1 += __shfl_xor(q1, off, 64);
        q2 += __shfl_xor(q2, off, 64); q3 += __shfl_xor(q3, off, 64);
    }
    if (lane < 4) {
        int slot = blockIdx.x & 63;
        float* ps = &ssum[slot * 16 + 4 * lane];
        float* pq = &ssq[slot * 16 + 4 * lane];
        atomicAdd(ps + 0, s0); atomicAdd(ps + 1, s1);
        atomicAdd(ps + 2, s2); atomicAdd(ps + 3, s3);
        atomicAdd(pq + 0, q0); atomicAdd(pq + 1, q1);
        atomicAdd(pq + 2, q2); atomicAdd(pq + 3, q3);
    }
}

// ---------------- fused BN-finalize + apply (per-layer stat slice) ----------------
__global__ void k_apply(const float* __restrict__ h,
                        const float* __restrict__ ssum, const float* __restrict__ ssq,
                        const float* __restrict__ g, const float* __restrict__ b,
                        float* __restrict__ x, h16* __restrict__ local, int colbase) {
    __shared__ float sscale[16], sshift[16];
    int t = threadIdx.x;
    if (t < 16) {
        float s = 0.f, q = 0.f;
        for (int sl = 0; sl < 64; sl++) {
            s += ssum[sl * 16 + t];
            q += ssq[sl * 16 + t];
        }
        float mean = s / (float)NN;
        float var = q / (float)NN - mean * mean;
        var = var > 0.f ? var : 0.f;
        float sc = g[t] / sqrtf(var + BNEPS);
        sscale[t] = sc;
        sshift[t] = b[t] - mean * sc;
    }
    __syncthreads();
    int i = blockIdx.x * 256 + t;
    int n = i >> 4, c = i & 15;
    float v = fmaf(h[i], sscale[c], sshift[c]);
    float e = v > 0.f ? v : expm1f(v);
    x[i] = e;
    local[(size_t)n * LOCP + colbase + c] = f2h(e);
}

// ---------------- BN finalize (GEMM layers): 64-slot reduce + self-clean ----------------
__global__ void k_bn_fin(float* __restrict__ ssum, float* __restrict__ ssq,
                         const float* __restrict__ g, const float* __restrict__ b,
                         float M, int C, float* __restrict__ scale, float* __restrict__ shift) {
    int c = blockIdx.x * blockDim.x + threadIdx.x;
    if (c >= C) return;
    float s = 0.f, q = 0.f;
    for (int sl = 0; sl < 64; sl++) {
        s += ssum[sl * C + c]; ssum[sl * C + c] = 0.f;
        q += ssq[sl * C + c];  ssq[sl * C + c] = 0.f;
    }
    float mean = s / M;
    float var = q / M - mean * mean;
    var = var > 0.f ? var : 0.f;
    float sc = g[c] / sqrtf(var + BNEPS);
    scale[c] = sc;
    shift[c] = b[c] - mean * sc;
}

// ---------------- weight prep: fragment-order Wt (hi+lo) ----------------
__global__ void k_wt(const float* __restrict__ W, const float* __restrict__ scale,
                     h16* __restrict__ WtH, h16* __restrict__ WtL,
                     int N, int Kin, int Kpad, int split, int gap) {
    int u = blockIdx.x * 256 + threadIdx.x;
    int nkc = Kpad >> 5;
    int total = (N >> 4) * nkc * 64;
    if (u >= total) return;
    int lane = u & 63;
    int fc = u >> 6;
    int kc = fc % nkc;
    int cs = fc / nkc;
    int col = cs * 16 + (lane & 15);
    int kbase = kc * 32 + ((lane >> 4) << 3);
    h8 hh, ll;
    #pragma unroll
    for (int j = 0; j < 8; j++) {
        int k = kbase + j;
        float v = 0.f;
        int kr = (k < split) ? k : (k - gap);
        bool valid = (k < split) ? (k < Kin) : (k >= split + gap && kr < Kin);
        if (valid) {
            v = W[(size_t)kr * N + col];
            if (scale) v *= scale[kr];
        }
        h16 hi = f2h(v);
        hh[j] = hi;
        ll[j] = f2h(v - h2f(hi));
    }
    *(h8*)(WtH + (size_t)u * 8) = hh;
    *(h8*)(WtL + (size_t)u * 8) = ll;
}

// ---------------- bias2 = bias + shift @ W (wave per output) ----------------
__global__ void k_bias2(const float* __restrict__ W, const float* __restrict__ bias,
                        const float* __restrict__ shift, float* __restrict__ bias2,
                        int N, int Kin) {
    int n = blockIdx.x;
    int lane = threadIdx.x;
    float acc = 0.f;
    if (shift) {
        for (int k = lane; k < Kin; k += 64)
            acc = fmaf(shift[k], W[(size_t)k * N + n], acc);
    }
    for (int off = 32; off; off >>= 1) acc += __shfl_down(acc, off, 64);
    if (lane == 0) bias2[n] = bias[n] + acc;
}

// ---------------- MFMA GEMM: 64x(NS*64) tile; B direct-from-global (fragment order);
//   A double-buffered LDS; XCD swizzle; branchless loads; manual 2x K-unroll ----------------
template <int NS, bool CONCAT, bool POOL>
__global__ __launch_bounds__(256) void k_gemm(
    const h16* __restrict__ A, int lda, int KA,
    const h16* __restrict__ WtH, const h16* __restrict__ WtL, int Kpad,
    const float* __restrict__ bias2, int Nc,
    const h16* __restrict__ Gp, const int* __restrict__ batch,
    int M,
    h16* __restrict__ C,
    float* __restrict__ ssum, float* __restrict__ ssq,
    unsigned* __restrict__ mx, unsigned* __restrict__ mn) {
    __shared__ h16 As0[2048];
    __shared__ h16 As1[2048];

    const int t = threadIdx.x;
    int bx = blockIdx.x, by = blockIdx.y;
    {
        int nbx = gridDim.x;
        int id = by * nbx + bx;
        int gs = nbx * 8;
        int nfull = (gridDim.y >> 3) * gs;
        if (id < nfull) {
            int grp = id / gs;
            int w_ = id - grp * gs;
            bx = w_ >> 3;
            by = grp * 8 + (w_ & 7);
        }
    }
    const int row0 = by * 64;
    const int col0 = bx * (NS * 64);
    const int w = t >> 6, lane = t & 63, quad = lane >> 4, m = lane & 15;
    const int nkc = Kpad >> 5;  // even for all layers

    f4 acc[NS][4];
    #pragma unroll
    for (int sp = 0; sp < NS; sp++)
        #pragma unroll
        for (int i = 0; i < 4; i++)
            #pragma unroll
            for (int j = 0; j < 4; j++) acc[sp][i][j] = 0.f;

    const int rl = ((t >> 6) << 4) | (t & 15);
    const int ch = (t >> 4) & 3;
    const int r = row0 + rl;
    const int rc = (r < M) ? r : (M - 1);  // clamped; invalid rows masked in epilogue
    int bg = 0;
    if (CONCAT) bg = batch[rc];
    const h16* Arow = A + (size_t)rc * lda;
    const h16* Grow = CONCAT ? (Gp + (size_t)bg * 1024 - lda) : nullptr;
    const int st = t * 8;
    const int fidx = quad * 128 + m * 8;
    const h16* bH[NS];
    const h16* bL[NS];
    #pragma unroll
    for (int sp = 0; sp < NS; sp++) {
        size_t o = ((size_t)((col0 >> 4) + w + 4 * sp) * nkc * 64 + lane) * 8;
        bH[sp] = WtH + o;
        bL[sp] = WtL + o;
    }

    auto LOADA = [&](int k0_, h8& av) {
        int k = k0_ + ch * 8;
        const h16* p = (CONCAT && k >= lda) ? (Grow + k) : (Arow + k);
        av = *(const h8*)p;
    };
    auto COMP = [&](const h16* buf, h8* bh, h8* bl) {
        #pragma unroll
        for (int rt = 0; rt < 4; rt++) {
            h8 af = *(const h8*)(buf + rt * 512 + fidx);
            #pragma unroll
            for (int sp = 0; sp < NS; sp++) {
                acc[sp][rt] = __builtin_amdgcn_mfma_f32_16x16x32_f16(af, bh[sp], acc[sp][rt], 0, 0, 0);
                acc[sp][rt] = __builtin_amdgcn_mfma_f32_16x16x32_f16(af, bl[sp], acc[sp][rt], 0, 0, 0);
            }
        }
    };

    h8 aA, aB;
    h8 bhA[NS], blA[NS], bhB[NS], blB[NS];
    LOADA(0, aA);
    #pragma unroll
    for (int sp = 0; sp < NS; sp++) {
        bhA[sp] = *(const h8*)bH[sp]; blA[sp] = *(const h8*)bL[sp];
        bH[sp] += 512; bL[sp] += 512;
    }

    for (int kt = 0; kt < nkc; kt += 2) {
        *(h8*)(As0 + st) = aA;
        LOADA((kt + 1) * 32, aB);
        #pragma unroll
        for (int sp = 0; sp < NS; sp++) {
            bhB[sp] = *(const h8*)bH[sp]; blB[sp] = *(const h8*)bL[sp];
            bH[sp] += 512; bL[sp] += 512;
        }
        __syncthreads();
        COMP(As0, bhA, blA);
        *(h8*)(As1 + st) = aB;
        if (kt + 2 < nkc) {
            LOADA((kt + 2) * 32, aA);
            #pragma unroll
            for (int sp = 0; sp < NS; sp++) {
                bhA[sp] = *(const h8*)bH[sp]; blA[sp] = *(const h8*)bL[sp];
                bH[sp] += 512; bL[sp] += 512;
            }
        }
        __syncthreads();
        COMP(As1, bhB, blB);
    }

    bool unig = true; int gblk = 0;
    if (POOL) {
        gblk = batch[min(row0, M - 1)];
        unig = (batch[min(row0 + 63, M - 1)] == gblk);
    }

    #pragma unroll
    for (int sp = 0; sp < NS; sp++) {
        const int col = col0 + (w + 4 * sp) * 16 + m;
        const float bi = bias2[col];
        float sv = 0.f, qv = 0.f;
        unsigned um = 0u, un = 0x7f800000u;
        #pragma unroll
        for (int rt = 0; rt < 4; rt++) {
            #pragma unroll
            for (int rg = 0; rg < 4; rg++) {
                int rr = row0 + rt * 16 + quad * 4 + rg;
                if (rr < M) {
                    float y = acc[sp][rt][rg] + bi;
                    y = y > 0.f ? y : 0.f;
                    if (!POOL) C[(size_t)rr * Nc + col] = f2h(y);
                    sv += y; qv += y * y;
                    if (POOL) {
                        unsigned ub = __float_as_uint(y);
                        if (unig) { um = max(um, ub); un = min(un, ub); }
                        else {
                            int gg = batch[rr];
                            atomicMax(&mx[gg * 1024 + col], ub);
                            atomicMin(&mn[gg * 1024 + col], ub);
                        }
                    }
                }
            }
        }
        sv += __shfl_xor(sv, 16, 64); sv += __shfl_xor(sv, 32, 64);
        qv += __shfl_xor(qv, 16, 64); qv += __shfl_xor(qv, 32, 64);
        if (POOL && unig) {
            um = max(um, (unsigned)__shfl_xor((int)um, 16, 64));
            um = max(um, (unsigned)__shfl_xor((int)um, 32, 64));
            un = min(un, (unsigned)__shfl_xor((int)un, 16, 64));
            un = min(un, (unsigned)__shfl_xor((int)un, 32, 64));
        }
        if (quad == 0) {
            int slot = by & 63;
            atomicAdd(&ssum[slot * Nc + col], sv);
            atomicAdd(&ssq[slot * Nc + col], qv);
            if (POOL && unig) {
                atomicMax(&mx[gblk * 1024 + col], um);
                atomicMin(&mn[gblk * 1024 + col], un);
            }
        }
    }
}

// ---------------- pooling helpers ----------------
__global__ void k_init_minmax(unsigned* __restrict__ mx, unsigned* __restrict__ mn) {
    int i = blockIdx.x * 256 + threadIdx.x;
    if (i < NGRAPH * 1024) { mx[i] = 0u; mn[i] = 0x7f800000u; }
}

__global__ void k_pool_fin(const unsigned* __restrict__ mx, const unsigned* __restrict__ mn,
                           const float* __restrict__ scale, const float* __restrict__ shift,
                           h16* __restrict__ pooled_h) {
    int i = blockIdx.x * 256 + threadIdx.x;
    if (i >= NGRAPH * 1024) return;
    int c = i & 1023;
    float sc = scale[c], sh = shift[c];
    float vmax = __uint_as_float(mx[i]);
    float vmin = __uint_as_float(mn[i]);
    float v = sc > 0.f ? fmaf(sc, vmax, sh) : fmaf(sc, vmin, sh);
    pooled_h[i] = f2h(v);
}

// ---------------- final fold + output ----------------
__global__ void k_fold(const float* __restrict__ scale, const float* __restrict__ shift,
                       const float* __restrict__ ow, const float* __restrict__ ob,
                       float* __restrict__ wprime, float* __restrict__ bprime) {
    int c = threadIdx.x;  // 128
    float w = ow[c];
    wprime[c] = scale[c] * w;
    float v = shift[c] * w;
    for (int off = 32; off; off >>= 1) v += __shfl_down(v, off, 64);
    __shared__ float l[2];
    if ((c & 63) == 0) l[c >> 6] = v;
    __syncthreads();
    if (c == 0) bprime[0] = l[0] + l[1] + ob[0];
}

__global__ void k_out(const h16* __restrict__ p3, const float* __restrict__ wprime,
                      const float* __restrict__ bprime, float* __restrict__ out) {
    int n = blockIdx.x * 256 + threadIdx.x;
    if (n >= NN) return;
    const h16* r = p3 + (size_t)n * 128;
    float acc = bprime[0];
    #pragma unroll
    for (int q = 0; q < 128; q++) acc = fmaf(h2f(r[q]), wprime[q], acc);
    out[n] = acc;
}

extern "C" void kernel_launch(void* const* d_in, const int* in_sizes, int n_in,
                              void* d_out, int out_size, void* d_ws, size_t ws_size,
                              hipStream_t stream) {
    const float* pos = (const float*)d_in[0];
    const float* nrm = (const float*)d_in[1];
    const float* cur = (const float*)d_in[2];
    const int* ei = (const int*)d_in[3];
    const int* src = ei;
    const int* dst = ei + NE;
    const int* batch = (const int*)d_in[4];
    const float* w_nb0 = (const float*)d_in[5];
    const float* b_nb0 = (const float*)d_in[6];
    const float* w_rt0 = (const float*)d_in[7];
    const float* w_nb = (const float*)d_in[8];
    const float* b_nb = (const float*)d_in[9];
    const float* w_rt = (const float*)d_in[10];
    const float* bn_g = (const float*)d_in[11];
    const float* bn_b = (const float*)d_in[12];
    const float* g_w1 = (const float*)d_in[13];
    const float* g_b1 = (const float*)d_in[14];
    const float* g_g1 = (const float*)d_in[15];
    const float* g_be1 = (const float*)d_in[16];
    const float* g_w2 = (const float*)d_in[17];
    const float* g_b2 = (const float*)d_in[18];
    const float* g_g2 = (const float*)d_in[19];
    const float* g_be2 = (const float*)d_in[20];
    const float* g_w3 = (const float*)d_in[21];
    const float* g_b3 = (const float*)d_in[22];
    const float* g_g3 = (const float*)d_in[23];
    const float* g_be3 = (const float*)d_in[24];
    const float* p_w1 = (const float*)d_in[25];
    const float* p_b1 = (const float*)d_in[26];
    const float* p_g1 = (const float*)d_in[27];
    const float* p_be1 = (const float*)d_in[28];
    const float* p_w2 = (const float*)d_in[29];
    const float* p_b2 = (const float*)d_in[30];
    const float* p_g2 = (const float*)d_in[31];
    const float* p_be2 = (const float*)d_in[32];
    const float* p_w3 = (const float*)d_in[33];
    const float* p_b3 = (const float*)d_in[34];
    const float* p_g3 = (const float*)d_in[35];
    const float* p_be3 = (const float*)d_in[36];
    const float* out_w = (const float*)d_in[37];
    const float* out_b = (const float*)d_in[38];
    float* out = (float*)d_out;

    char* base = (char*)d_ws;
    size_t off = 0;
    auto alloc = [&](size_t bytes) -> void* {
        void* p = base + off;
        off = (off + bytes + 255) & ~(size_t)255;
        return p;
    };

    // --- overlay arena region (dead after phase 1) doubles as WtH arena (phase >= 2) ---
    int* cnt = (int*)alloc((size_t)NN * 4);
    int* cursor = (int*)alloc((size_t)NN * 4);
    float* sg_sum = (float*)alloc(DEPTH * 64 * 16 * 4);   // per-layer slices
    float* sg_sq = (float*)alloc(DEPTH * 64 * 16 * 4);
    int* row_start = (int*)alloc((size_t)(NN + 1) * 4);
    float* inv_cnt = (float*)alloc((size_t)NN * 4);
    int* bsum = (int*)alloc(512 * 4);
    h16* wt_arena = (h16*)base;                        // overlays the arrays above
    h16* WtH_g1 = wt_arena + 0;        // 256*192
    h16* WtH_g2 = wt_arena + 49152;    // 512*256
    h16* WtH_g3 = wt_arena + 180224;   // 1024*512  (ends 704512)
    h16* WtH_p1 = wt_arena + 0;        // 512*1216
    h16* WtH_p2 = wt_arena + 622592;   // 256*512
    h16* WtH_p3 = wt_arena + 753664;   // 128*256   (ends 786432 halfs; fits)

    // --- GEMM stat slots (live phases 2-3; self-cleaned by bn_fin) ---
    float* gs_sum = (float*)alloc(64 * 1024 * 4);
    float* gs_sq = (float*)alloc(64 * 1024 * 4);
    size_t zend = off;  // memset [0, zend)

    // --- WtL arena (fully written by k_wt) ---
    h16* wtlo_arena = (h16*)alloc((size_t)786432 * 2);
    h16* WtL_g1 = wtlo_arena + 0;
    h16* WtL_g2 = wtlo_arena + 49152;
    h16* WtL_g3 = wtlo_arena + 180224;
    h16* WtL_p1 = wtlo_arena + 0;
    h16* WtL_p2 = wtlo_arena + 622592;
    h16* WtL_p3 = wtlo_arena + 753664;

    // --- small persistent ---
    const int CS[6] = {256, 512, 1024, 512, 256, 128};
    float* sc_arr[6];
    float* sh_arr[6];
    for (int i = 0; i < 6; i++) {
        sc_arr[i] = (float*)alloc(CS[i] * 4);
        sh_arr[i] = (float*)alloc(CS[i] * 4);
    }
    unsigned* mx = (unsigned*)alloc(NGRAPH * 1024 * 4);
    unsigned* mn = (unsigned*)alloc(NGRAPH * 1024 * 4);
    h16* pooled_h = (h16*)alloc(NGRAPH * 1024 * 2);
    float* wprime = (float*)alloc(128 * 4);
    float* bprime = (float*)alloc(256);
    float* bias2 = (float*)alloc(2688 * 4);
    float* b2_g1 = bias2 + 0;
    float* b2_g2 = bias2 + 256;
    float* b2_g3 = bias2 + 768;
    float* b2_p1 = bias2 + 1792;
    float* b2_p2 = bias2 + 2304;
    float* b2_p3 = bias2 + 2560;

    // --- local (f16, stride 192 with zero pad) ---
    h16* local = (h16*)alloc((size_t)NN * LOCP * 2);   // 38.4 MB

    // --- big overlay region O ---
    size_t O = off;
    float* x_cur = (float*)(base + O);                       // 6.4 MB
    float* h_buf = (float*)(base + O + (size_t)NN * 64);     // 6.4 MB
    int* csr = (int*)(base + O + (size_t)NN * 128);          // 12.8 MB (dead before g1)
    h16* g1b = (h16*)(base + O);                             // 51.2 MB
    h16* g2b = (h16*)(base + O + (size_t)NN * 512);          // 102.4 MB
    h16* p1b = g2b;
    h16* p2b = g1b;
    h16* p3b = local;
    size_t need = O + (size_t)NN * 512 + (size_t)NN * 1024;

    if (need > ws_size) return;

    const int NB = (NN + 255) / 256;  // 391
    hipMemsetAsync(base, 0, zend, stream);
    k_init_minmax<<<32, 256, 0, stream>>>(mx, mn);
    k_count<<<NE / 256, 256, 0, stream>>>(dst, cnt);
    k_scan1<<<NB, 256, 0, stream>>>(cnt, row_start, bsum);
    k_scan2<<<1, 512, 0, stream>>>(bsum, NB);
    k_scan3<<<NB, 256, 0, stream>>>(cnt, row_start, bsum, inv_cnt);
    k_fill<<<NE / 256, 256, 0, stream>>>(src, dst, row_start, cursor, csr);
    k_build_x0<<<(NN + 255) / 256, 256, 0, stream>>>(pos, nrm, cur, x_cur, local);

    for (int i = 0; i < DEPTH; i++) {
        const float* wn = (i == 0) ? w_nb0 : (w_nb + (size_t)(i - 1) * 256);
        const float* bnb = (i == 0) ? b_nb0 : (b_nb + (size_t)(i - 1) * 16);
        const float* wr = (i == 0) ? w_rt0 : (w_rt + (size_t)(i - 1) * 256);
        int kin = (i == 0) ? 7 : 16;
        float* ls = sg_sum + i * 1024;
        float* lq = sg_sq + i * 1024;
        k_sage<<<(NN + 63) / 64, 256, 0, stream>>>(x_cur, row_start, csr, inv_cnt,
                                                   wn, bnb, wr, kin, h_buf, ls, lq);
        k_apply<<<NN * 16 / 256, 256, 0, stream>>>(h_buf, ls, lq, bn_g + i * 16, bn_b + i * 16,
                                                   x_cur, local, i * 16);
    }

    const int GRY = (NN + 63) / 64;  // 1563

    // g1: local[192 zero-padded] -> 256
    k_wt<<<(256 * 192 / 8 + 255) / 256, 256, 0, stream>>>(g_w1, nullptr, WtH_g1, WtL_g1, 256, 167, 192, 167, 0);
    k_bias2<<<256, 64, 0, stream>>>(g_w1, g_b1, nullptr, b2_g1, 256, 167);
    k_gemm<2, false, false><<<dim3(2, GRY), 256, 0, stream>>>(
        local, LOCP, 192, WtH_g1, WtL_g1, 192, b2_g1, 256, nullptr, batch, NN,
        g1b, gs_sum, gs_sq, nullptr, nullptr);
    k_bn_fin<<<1, 256, 0, stream>>>(gs_sum, gs_sq, g_g1, g_be1, (float)NN, 256, sc_arr[0], sh_arr[0]);

    // g2: 256 -> 512 (affine folded)
    k_wt<<<(512 * 256 / 8 + 255) / 256, 256, 0, stream>>>(g_w2, sc_arr[0], WtH_g2, WtL_g2, 512, 256, 256, 256, 0);
    k_bias2<<<512, 64, 0, stream>>>(g_w2, g_b2, sh_arr[0], b2_g2, 512, 256);
    k_gemm<2, false, false><<<dim3(4, GRY), 256, 0, stream>>>(
        g1b, 256, 256, WtH_g2, WtL_g2, 256, b2_g2, 512, nullptr, batch, NN,
        g2b, gs_sum, gs_sq, nullptr, nullptr);
    k_bn_fin<<<2, 256, 0, stream>>>(gs_sum, gs_sq, g_g2, g_be2, (float)NN, 512, sc_arr[1], sh_arr[1]);

    // g3: 512 -> 1024, fused pooling
    k_wt<<<(1024 * 512 / 8 + 255) / 256, 256, 0, stream>>>(g_w3, sc_arr[1], WtH_g3, WtL_g3, 1024, 512, 512, 512, 0);
    k_bias2<<<1024, 64, 0, stream>>>(g_w3, g_b3, sh_arr[1], b2_g3, 1024, 512);
    k_gemm<2, false, true><<<dim3(8, GRY), 256, 0, stream>>>(
        g2b, 512, 512, WtH_g3, WtL_g3, 512, b2_g3, 1024, nullptr, batch, NN,
        nullptr, gs_sum, gs_sq, mx, mn);
    k_bn_fin<<<4, 256, 0, stream>>>(gs_sum, gs_sq, g_g3, g_be3, (float)NN, 1024, sc_arr[2], sh_arr[2]);
    k_pool_fin<<<32, 256, 0, stream>>>(mx, mn, sc_arr[2], sh_arr[2], pooled_h);

    // p1: concat(local[192], pooled[1024]) -> 512   (boundary at 192, gap=25)
    k_wt<<<(512 * 1216 / 8 + 255) / 256, 256, 0, stream>>>(p_w1, nullptr, WtH_p1, WtL_p1, 512, 1191, 1216, 167, 25);
    k_bias2<<<512, 64, 0, stream>>>(p_w1, p_b1, nullptr, b2_p1, 512, 1191);
    k_gemm<2, true, false><<<dim3(4, GRY), 256, 0, stream>>>(
        local, LOCP, 1216, WtH_p1, WtL_p1, 1216, b2_p1, 512, pooled_h, batch, NN,
        p1b, gs_sum, gs_sq, nullptr, nullptr);
    k_bn_fin<<<2, 256, 0, stream>>>(gs_sum, gs_sq, p_g1, p_be1, (float)NN, 512, sc_arr[3], sh_arr[3]);

    // p2: 512 -> 256
    k_wt<<<(256 * 512 / 8 + 255) / 256, 256, 0, stream>>>(p_w2, sc_arr[3], WtH_p2, WtL_p2, 256, 512, 512, 512, 0);
    k_bias2<<<256, 64, 0, stream>>>(p_w2, p_b2, sh_arr[3], b2_p2, 256, 512);
    k_gemm<2, false, false><<<dim3(2, GRY), 256, 0, stream>>>(
        p1b, 512, 512, WtH_p2, WtL_p2, 512, b2_p2, 256, nullptr, batch, NN,
        p2b, gs_sum, gs_sq, nullptr, nullptr);
    k_bn_fin<<<1, 256, 0, stream>>>(gs_sum, gs_sq, p_g2, p_be2, (float)NN, 256, sc_arr[4], sh_arr[4]);

    // p3: 256 -> 128
    k_wt<<<(128 * 256 / 8 + 255) / 256, 256, 0, stream>>>(p_w3, sc_arr[4], WtH_p3, WtL_p3, 128, 256, 256, 256, 0);
    k_bias2<<<128, 64, 0, stream>>>(p_w3, p_b3, sh_arr[4], b2_p3, 128, 256);
    k_gemm<2, false, false><<<dim3(1, GRY), 256, 0, stream>>>(
        p2b, 256, 256, WtH_p3, WtL_p3, 256, b2_p3, 128, nullptr, batch, NN,
        p3b, gs_sum, gs_sq, nullptr, nullptr);
    k_bn_fin<<<1, 128, 0, stream>>>(gs_sum, gs_sq, p_g3, p_be3, (float)NN, 128, sc_arr[5], sh_arr[5]);

    k_fold<<<1, 128, 0, stream>>>(sc_arr[5], sh_arr[5], out_w, out_b, wprime, bprime);
    k_out<<<(NN + 255) / 256, 256, 0, stream>>>(p3b, wprime, bprime, out);
}